// Round 1
// baseline (367.054 us; speedup 1.0000x reference)
//
#include <hip/hip_runtime.h>
#include <hip/hip_bf16.h>
#include <stdint.h>

// Problem constants
// B=128 STREAM=512 IN_CH=4 EXTRA=5 GROUPS=2 DEPTH=3 STEP=16 LENGTH=32 RNN=256 OUT=10
// C=10 SIG_C=1110 W=31 F=2220, padded K = 2240, GEMM M = 31*128 = 3968, N = 768

typedef _Float16 f16;
typedef f16  f16x8 __attribute__((ext_vector_type(8)));
typedef float f32x4 __attribute__((ext_vector_type(4)));

#define ASYNC16(gp, lp) __builtin_amdgcn_global_load_lds( \
    (const __attribute__((address_space(1))) void*)(gp),  \
    (__attribute__((address_space(3))) void*)(lp), 16, 0, 0)

// ---------------------------------------------------------------- K0: weight conversion
__global__ __launch_bounds__(256) void conv_kernel(const float* __restrict__ Wih,
                                                   const float* __restrict__ Whh,
                                                   f16* __restrict__ wih16,
                                                   f16* __restrict__ whh16) {
    int idx = blockIdx.x * 256 + threadIdx.x;
    const int NIH = 768 * 2240;
    if (idx < NIH) {
        int r = idx / 2240, k = idx - r * 2240;
        wih16[idx] = (f16)(k < 2220 ? Wih[r * 2220 + k] : 0.0f);
    } else if (idx < NIH + 768 * 256) {
        int j = idx - NIH;
        whh16[j] = (f16)Whh[j];
    }
}

// ---------------------------------------------------------------- K1: signatures
// one block (64 threads) per chain (bg, w); 7936 blocks
__global__ __launch_bounds__(64) void sig_kernel(const float* __restrict__ x,
                                                 const float* __restrict__ W_aug,
                                                 f16* __restrict__ sig16) {
    int bid = blockIdx.x;
    int w = bid % 31;
    int bg = bid / 31;
    int b = bg >> 1, g = bg & 1;
    __shared__ float dxs[31][10];
    int tid = threadIdx.x;
    if (tid < 31) {
        int s = w * 16 + tid;
        const float4 x0 = *(const float4*)(x + ((size_t)b * 512 + s) * 4);
        const float4 x1 = *(const float4*)(x + ((size_t)b * 512 + s + 1) * 4);
        float d0 = x1.x - x0.x, d1 = x1.y - x0.y, d2 = x1.z - x0.z, d3 = x1.w - x0.w;
        dxs[tid][0] = d0; dxs[tid][1] = d1; dxs[tid][2] = d2; dxs[tid][3] = d3;
        dxs[tid][4] = 1.0f / 511.0f;
#pragma unroll
        for (int e = 0; e < 5; e++) {
            const float* wa = W_aug + (g * 5 + e) * 4;
            dxs[tid][5 + e] = d0 * wa[0] + d1 * wa[1] + d2 * wa[2] + d3 * wa[3];
        }
    }
    __syncthreads();
    size_t base = ((size_t)(w * 128 + b)) * 2240 + (size_t)g * 1110;
    if (tid < 50) {
        int p0 = 2 * tid, p1 = p0 + 1;
        int i0 = p0 / 10, j0 = p0 % 10, j1 = j0 + 1;
        float s3a[10], s3b[10];
#pragma unroll
        for (int k = 0; k < 10; k++) { s3a[k] = 0.f; s3b[k] = 0.f; }
        float s2a = 0.f, s2b = 0.f, s1 = 0.f;
        for (int l = 0; l < 31; l++) {
            float dx[10];
#pragma unroll
            for (int c = 0; c < 10; c++) dx[c] = dxs[l][c];
            // newS3[ijk] = S3 + S2*dxk + S1_i*dxj*dxk/2 + dxi*dxj*dxk/6
            float t0 = s1 + dx[i0] * (1.0f / 3.0f);
            float a0 = s2a + t0 * (0.5f * dx[j0]);
            float a1 = s2b + t0 * (0.5f * dx[j1]);
#pragma unroll
            for (int k = 0; k < 10; k++) { s3a[k] += a0 * dx[k]; s3b[k] += a1 * dx[k]; }
            // newS2[ij] = S2 + S1_i*dxj + dxi*dxj/2
            float u = s1 + 0.5f * dx[i0];
            s2a += u * dx[j0];
            s2b += u * dx[j1];
            s1 += dx[i0];
        }
        sig16[base + 10 + p0] = (f16)s2a;
        sig16[base + 10 + p1] = (f16)s2b;
#pragma unroll
        for (int k = 0; k < 10; k++) {
            sig16[base + 110 + p0 * 10 + k] = (f16)s3a[k];
            sig16[base + 110 + p1 * 10 + k] = (f16)s3b[k];
        }
    } else if (tid < 60) {
        int c = tid - 50;
        float s = 0.f;
        for (int l = 0; l < 31; l++) s += dxs[l][c];
        sig16[base + c] = (f16)s;
    }
    if (g == 1 && tid < 20)
        sig16[((size_t)(w * 128 + b)) * 2240 + 2220 + tid] = (f16)0.0f;
}

// ---------------------------------------------------------------- K2: gi = sig @ W_ih.T + b_ih
// f16 MFMA 16x16x32; 128x128 tile, 4 waves (2x2), K=2240 in 70 steps of 32
__global__ __launch_bounds__(256) void gemm_kernel(const f16* __restrict__ A,     // 3968 x 2240
                                                   const f16* __restrict__ Bw,    // 768 x 2240 (W_ih rows)
                                                   const float* __restrict__ bias,
                                                   float* __restrict__ Cout) {    // 3968 x 768
    __shared__ __align__(16) f16 As[128 * 32];
    __shared__ __align__(16) f16 Bs[128 * 32];
    const int tid = threadIdx.x, lane = tid & 63, wid = tid >> 6;
    const int wm = wid >> 1, wn = wid & 1;
    const int Mbase = blockIdx.y * 128, Nbase = blockIdx.x * 128;
    const int lr = lane >> 2;   // row within 16-row group
    const int lk = lane & 3;    // k offset * 8 elements
    const int l16 = lane & 15, quad = lane >> 4;
    f32x4 acc[4][4];
#pragma unroll
    for (int mt = 0; mt < 4; mt++)
#pragma unroll
        for (int nt = 0; nt < 4; nt++) acc[mt][nt] = (f32x4){0.f, 0.f, 0.f, 0.f};

    for (int kt = 0; kt < 70; kt++) {
        const int k0 = kt * 32;
#pragma unroll
        for (int q = 0; q < 2; q++) {
            int r0 = wid * 32 + q * 16;
            const f16* ga = A + (size_t)(Mbase + r0 + lr) * 2240 + k0 + lk * 8;
            ASYNC16(ga, &As[r0 * 32]);
            const f16* gb = Bw + (size_t)(Nbase + r0 + lr) * 2240 + k0 + lk * 8;
            ASYNC16(gb, &Bs[r0 * 32]);
        }
        __syncthreads();
        f16x8 af[4], bf[4];
#pragma unroll
        for (int mt = 0; mt < 4; mt++)
            af[mt] = *(const f16x8*)&As[(wm * 64 + mt * 16 + l16) * 32 + quad * 8];
#pragma unroll
        for (int nt = 0; nt < 4; nt++)
            bf[nt] = *(const f16x8*)&Bs[(wn * 64 + nt * 16 + l16) * 32 + quad * 8];
#pragma unroll
        for (int mt = 0; mt < 4; mt++)
#pragma unroll
            for (int nt = 0; nt < 4; nt++)
                acc[mt][nt] = __builtin_amdgcn_mfma_f32_16x16x32_f16(af[mt], bf[nt], acc[mt][nt], 0, 0, 0);
        __syncthreads();
    }
#pragma unroll
    for (int mt = 0; mt < 4; mt++)
#pragma unroll
        for (int nt = 0; nt < 4; nt++) {
            int col = Nbase + wn * 64 + nt * 16 + l16;
            float bv = bias[col];
#pragma unroll
            for (int rr = 0; rr < 4; rr++) {
                int row = Mbase + wm * 64 + mt * 16 + quad * 4 + rr;
                Cout[(size_t)row * 768 + col] = acc[mt][nt][rr] + bv;
            }
        }
}

// ---------------------------------------------------------------- K3: GRU scan + output head
// 8 blocks x 256 threads; block owns 16 batch rows; no inter-block communication.
__global__ __launch_bounds__(256) void gru_kernel(const float* __restrict__ gi,     // 3968 x 768 (t-major)
                                                  const f16* __restrict__ whh16,    // 768 x 256
                                                  const float* __restrict__ b_hh,   // 768
                                                  const float* __restrict__ W_out,  // 10 x 256
                                                  const float* __restrict__ b_out,  // 10
                                                  float* __restrict__ out) {        // 128 x 10
    __shared__ __align__(16) f16 h16[16 * 264];   // row stride 264 (pad) for 2-way-free b128 reads
    __shared__ float hf[16 * 257];
    const int tid = threadIdx.x, lane = tid & 63, wid = tid >> 6;
    const int b0 = blockIdx.x * 16;
    const int quad = lane >> 4, l16 = lane & 15;
    for (int i = tid; i < 16 * 264; i += 256) h16[i] = (f16)0.0f;
    float bhh[12];
#pragma unroll
    for (int gs = 0; gs < 3; gs++)
#pragma unroll
        for (int tc = 0; tc < 4; tc++)
            bhh[gs * 4 + tc] = b_hh[gs * 256 + wid * 64 + tc * 16 + l16];
    float hm[16];   // fp32 master h: [tc][rr] -> h[quad*4+rr][wid*64+tc*16+l16]
#pragma unroll
    for (int i = 0; i < 16; i++) hm[i] = 0.f;
    __syncthreads();

    for (int t = 0; t < 31; t++) {
        f16x8 af[8];
#pragma unroll
        for (int kt = 0; kt < 8; kt++)
            af[kt] = *(const f16x8*)&h16[l16 * 264 + kt * 32 + quad * 8];
        f32x4 acc[12];
#pragma unroll
        for (int u = 0; u < 12; u++) acc[u] = (f32x4){0.f, 0.f, 0.f, 0.f};
#pragma unroll
        for (int kt = 0; kt < 8; kt++) {
#pragma unroll
            for (int gs = 0; gs < 3; gs++)
#pragma unroll
                for (int tc = 0; tc < 4; tc++) {
                    int n = gs * 256 + wid * 64 + tc * 16 + l16;
                    f16x8 bf = *(const f16x8*)&whh16[(size_t)n * 256 + kt * 32 + quad * 8];
                    acc[gs * 4 + tc] = __builtin_amdgcn_mfma_f32_16x16x32_f16(af[kt], bf, acc[gs * 4 + tc], 0, 0, 0);
                }
        }
        float gv[12][4];
#pragma unroll
        for (int gs = 0; gs < 3; gs++)
#pragma unroll
            for (int tc = 0; tc < 4; tc++) {
                int col = gs * 256 + wid * 64 + tc * 16 + l16;
#pragma unroll
                for (int rr = 0; rr < 4; rr++) {
                    int row = t * 128 + b0 + quad * 4 + rr;
                    gv[gs * 4 + tc][rr] = gi[(size_t)row * 768 + col];
                }
            }
        __syncthreads();   // all h16 reads complete before overwrite
#pragma unroll
        for (int tc = 0; tc < 4; tc++)
#pragma unroll
            for (int rr = 0; rr < 4; rr++) {
                float ghr = acc[0 * 4 + tc][rr] + bhh[0 * 4 + tc];
                float ghz = acc[1 * 4 + tc][rr] + bhh[1 * 4 + tc];
                float ghn = acc[2 * 4 + tc][rr] + bhh[2 * 4 + tc];
                float rg = 1.f / (1.f + expf(-(gv[0 * 4 + tc][rr] + ghr)));
                float zg = 1.f / (1.f + expf(-(gv[1 * 4 + tc][rr] + ghz)));
                float ng = tanhf(gv[2 * 4 + tc][rr] + rg * ghn);
                float h = (1.f - zg) * ng + zg * hm[tc * 4 + rr];
                hm[tc * 4 + rr] = h;
                int r = quad * 4 + rr, c = wid * 64 + tc * 16 + l16;
                h16[r * 264 + c] = (f16)h;
            }
        __syncthreads();
    }
    // output head
#pragma unroll
    for (int tc = 0; tc < 4; tc++)
#pragma unroll
        for (int rr = 0; rr < 4; rr++) {
            int r = quad * 4 + rr, c = wid * 64 + tc * 16 + l16;
            hf[r * 257 + c] = hm[tc * 4 + rr];
        }
    __syncthreads();
    if (tid < 160) {
        int r = tid / 10, oc = tid - r * 10;
        float s = b_out[oc];
        for (int k = 0; k < 256; k++) s += hf[r * 257 + k] * W_out[oc * 256 + k];
        out[(b0 + r) * 10 + oc] = 1.f / (1.f + expf(-s));
    }
}

// ---------------------------------------------------------------- launch
extern "C" void kernel_launch(void* const* d_in, const int* in_sizes, int n_in,
                              void* d_out, int out_size, void* d_ws, size_t ws_size,
                              hipStream_t stream) {
    const float* x     = (const float*)d_in[0];
    const float* W_aug = (const float*)d_in[1];
    // d_in[2] = b_aug — cancels in dx, unused
    const float* W_ih  = (const float*)d_in[3];
    const float* W_hh  = (const float*)d_in[4];
    const float* b_ih  = (const float*)d_in[5];
    const float* b_hh  = (const float*)d_in[6];
    const float* W_out = (const float*)d_in[7];
    const float* b_out = (const float*)d_in[8];
    float* out = (float*)d_out;

    char* ws = (char*)d_ws;
    const size_t SIG_BYTES = (size_t)3968 * 2240 * 2;          // 17,776,640
    const size_t WIH_BYTES = (size_t)768 * 2240 * 2;           //  3,440,640
    const size_t WHH_BYTES = (size_t)768 * 256 * 2;            //    393,216
    const size_t GI_BYTES  = (size_t)3968 * 768 * 4;           // 12,189,696
    if (ws_size < SIG_BYTES + WIH_BYTES + WHH_BYTES + GI_BYTES) return;
    f16* sig16 = (f16*)ws;
    f16* wih16 = (f16*)(ws + SIG_BYTES);
    f16* whh16 = (f16*)(ws + SIG_BYTES + WIH_BYTES);
    float* giw = (float*)(ws + SIG_BYTES + WIH_BYTES + WHH_BYTES);

    hipLaunchKernelGGL(conv_kernel, dim3(7488), dim3(256), 0, stream, W_ih, W_hh, wih16, whh16);
    hipLaunchKernelGGL(sig_kernel, dim3(7936), dim3(64), 0, stream, x, W_aug, sig16);
    hipLaunchKernelGGL(gemm_kernel, dim3(6, 31), dim3(256), 0, stream, sig16, wih16, b_ih, giw);
    hipLaunchKernelGGL(gru_kernel, dim3(8), dim3(256), 0, stream, giw, whh16, b_hh, W_out, b_out, out);
}

// Round 2
// 297.724 us; speedup vs baseline: 1.2329x; 1.2329x over previous
//
#include <hip/hip_runtime.h>
#include <hip/hip_bf16.h>
#include <stdint.h>

// Problem constants
// B=128 STREAM=512 IN_CH=4 EXTRA=5 GROUPS=2 DEPTH=3 STEP=16 LENGTH=32 RNN=256 OUT=10
// C=10 SIG_C=1110 W=31 F=2220, padded K = 2240, GEMM M = 31*128 = 3968, N = 768

typedef _Float16 f16;
typedef f16  f16x8 __attribute__((ext_vector_type(8)));
typedef float f32x4 __attribute__((ext_vector_type(4)));

#define ASYNC16(gp, lp) __builtin_amdgcn_global_load_lds( \
    (const __attribute__((address_space(1))) void*)(gp),  \
    (__attribute__((address_space(3))) void*)(lp), 16, 0, 0)

// ---------------------------------------------------------------- K0: weight conversion
__global__ __launch_bounds__(256) void conv_kernel(const float* __restrict__ Wih,
                                                   const float* __restrict__ Whh,
                                                   f16* __restrict__ wih16,
                                                   f16* __restrict__ whh16) {
    int idx = blockIdx.x * 256 + threadIdx.x;
    const int NIH = 768 * 2240;
    if (idx < NIH) {
        int r = idx / 2240, k = idx - r * 2240;
        wih16[idx] = (f16)(k < 2220 ? Wih[r * 2220 + k] : 0.0f);
    } else if (idx < NIH + 768 * 256) {
        int j = idx - NIH;
        whh16[j] = (f16)Whh[j];
    }
}

// ---------------------------------------------------------------- K1: signatures
// one block (64 threads) per chain (bg, w); 7936 blocks
__global__ __launch_bounds__(64) void sig_kernel(const float* __restrict__ x,
                                                 const float* __restrict__ W_aug,
                                                 f16* __restrict__ sig16) {
    int bid = blockIdx.x;
    int w = bid % 31;
    int bg = bid / 31;
    int b = bg >> 1, g = bg & 1;
    __shared__ float dxs[31][10];
    int tid = threadIdx.x;
    if (tid < 31) {
        int s = w * 16 + tid;
        const float4 x0 = *(const float4*)(x + ((size_t)b * 512 + s) * 4);
        const float4 x1 = *(const float4*)(x + ((size_t)b * 512 + s + 1) * 4);
        float d0 = x1.x - x0.x, d1 = x1.y - x0.y, d2 = x1.z - x0.z, d3 = x1.w - x0.w;
        dxs[tid][0] = d0; dxs[tid][1] = d1; dxs[tid][2] = d2; dxs[tid][3] = d3;
        dxs[tid][4] = 1.0f / 511.0f;
#pragma unroll
        for (int e = 0; e < 5; e++) {
            const float* wa = W_aug + (g * 5 + e) * 4;
            dxs[tid][5 + e] = d0 * wa[0] + d1 * wa[1] + d2 * wa[2] + d3 * wa[3];
        }
    }
    __syncthreads();
    size_t base = ((size_t)(w * 128 + b)) * 2240 + (size_t)g * 1110;
    if (tid < 50) {
        int p0 = 2 * tid, p1 = p0 + 1;
        int i0 = p0 / 10, j0 = p0 % 10, j1 = j0 + 1;
        float s3a[10], s3b[10];
#pragma unroll
        for (int k = 0; k < 10; k++) { s3a[k] = 0.f; s3b[k] = 0.f; }
        float s2a = 0.f, s2b = 0.f, s1 = 0.f;
        for (int l = 0; l < 31; l++) {
            float dx[10];
#pragma unroll
            for (int c = 0; c < 10; c++) dx[c] = dxs[l][c];
            float t0 = s1 + dx[i0] * (1.0f / 3.0f);
            float a0 = s2a + t0 * (0.5f * dx[j0]);
            float a1 = s2b + t0 * (0.5f * dx[j1]);
#pragma unroll
            for (int k = 0; k < 10; k++) { s3a[k] += a0 * dx[k]; s3b[k] += a1 * dx[k]; }
            float u = s1 + 0.5f * dx[i0];
            s2a += u * dx[j0];
            s2b += u * dx[j1];
            s1 += dx[i0];
        }
        sig16[base + 10 + p0] = (f16)s2a;
        sig16[base + 10 + p1] = (f16)s2b;
#pragma unroll
        for (int k = 0; k < 10; k++) {
            sig16[base + 110 + p0 * 10 + k] = (f16)s3a[k];
            sig16[base + 110 + p1 * 10 + k] = (f16)s3b[k];
        }
    } else if (tid < 60) {
        int c = tid - 50;
        float s = 0.f;
        for (int l = 0; l < 31; l++) s += dxs[l][c];
        sig16[base + c] = (f16)s;
    }
    if (g == 1 && tid < 20)
        sig16[((size_t)(w * 128 + b)) * 2240 + 2220 + tid] = (f16)0.0f;
}

// ---------------------------------------------------------------- K2: gi = sig @ W_ih.T + b_ih (+ b_hh for r,z gates)
__global__ __launch_bounds__(256) void gemm_kernel(const f16* __restrict__ A,     // 3968 x 2240
                                                   const f16* __restrict__ Bw,    // 768 x 2240 (W_ih rows)
                                                   const float* __restrict__ bias,
                                                   const float* __restrict__ bhh,
                                                   float* __restrict__ Cout) {    // 3968 x 768
    __shared__ __align__(16) f16 As[128 * 32];
    __shared__ __align__(16) f16 Bs[128 * 32];
    const int tid = threadIdx.x, lane = tid & 63, wid = tid >> 6;
    const int wm = wid >> 1, wn = wid & 1;
    const int Mbase = blockIdx.y * 128, Nbase = blockIdx.x * 128;
    const int lr = lane >> 2;
    const int lk = lane & 3;
    const int l16 = lane & 15, quad = lane >> 4;
    f32x4 acc[4][4];
#pragma unroll
    for (int mt = 0; mt < 4; mt++)
#pragma unroll
        for (int nt = 0; nt < 4; nt++) acc[mt][nt] = (f32x4){0.f, 0.f, 0.f, 0.f};

    for (int kt = 0; kt < 70; kt++) {
        const int k0 = kt * 32;
#pragma unroll
        for (int q = 0; q < 2; q++) {
            int r0 = wid * 32 + q * 16;
            const f16* ga = A + (size_t)(Mbase + r0 + lr) * 2240 + k0 + lk * 8;
            ASYNC16(ga, &As[r0 * 32]);
            const f16* gb = Bw + (size_t)(Nbase + r0 + lr) * 2240 + k0 + lk * 8;
            ASYNC16(gb, &Bs[r0 * 32]);
        }
        __syncthreads();
        f16x8 af[4], bf[4];
#pragma unroll
        for (int mt = 0; mt < 4; mt++)
            af[mt] = *(const f16x8*)&As[(wm * 64 + mt * 16 + l16) * 32 + quad * 8];
#pragma unroll
        for (int nt = 0; nt < 4; nt++)
            bf[nt] = *(const f16x8*)&Bs[(wn * 64 + nt * 16 + l16) * 32 + quad * 8];
#pragma unroll
        for (int mt = 0; mt < 4; mt++)
#pragma unroll
            for (int nt = 0; nt < 4; nt++)
                acc[mt][nt] = __builtin_amdgcn_mfma_f32_16x16x32_f16(af[mt], bf[nt], acc[mt][nt], 0, 0, 0);
        __syncthreads();
    }
#pragma unroll
    for (int mt = 0; mt < 4; mt++)
#pragma unroll
        for (int nt = 0; nt < 4; nt++) {
            int col = Nbase + wn * 64 + nt * 16 + l16;
            float bv = bias[col] + (col < 512 ? bhh[col] : 0.0f);   // fold b_hh into r,z gates
#pragma unroll
            for (int rr = 0; rr < 4; rr++) {
                int row = Mbase + wm * 64 + mt * 16 + quad * 4 + rr;
                Cout[(size_t)row * 768 + col] = acc[mt][nt][rr] + bv;
            }
        }
}

// ---------------------------------------------------------------- K3: GRU scan + output head
// 8 blocks x 512 threads (8 waves). Block owns 16 batch rows.
// Wave wid owns h-columns [wid*32, wid*32+32) for ALL 3 gates -> update is wave-local.
// W_hh fragments live in registers for the whole scan (no per-step L2 stream).
__global__ __launch_bounds__(512, 2) void gru_kernel(const float* __restrict__ gi,     // 3968 x 768 (t-major)
                                                     const f16* __restrict__ whh16,    // 768 x 256
                                                     const float* __restrict__ b_hh,   // 768
                                                     const float* __restrict__ W_out,  // 10 x 256
                                                     const float* __restrict__ b_out,  // 10
                                                     float* __restrict__ out) {        // 128 x 10
    __shared__ __align__(16) f16 h16[16 * 264];   // padded stride: b128 reads 2-way-free
    __shared__ float hf[16 * 257];
    const int tid = threadIdx.x, lane = tid & 63, wid = tid >> 6;   // wid 0..7
    const int quad = lane >> 4, l16 = lane & 15;
    const int b0 = blockIdx.x * 16;
    const int hc0 = wid * 32;

    for (int i = tid; i < 16 * 264; i += 512) h16[i] = (f16)0.0f;

    // resident W_hh fragments: bf[gate][tc][kt], 48 x f16x8 = 192 VGPRs
    f16x8 bf[3][2][8];
#pragma unroll
    for (int gs = 0; gs < 3; gs++)
#pragma unroll
        for (int tc = 0; tc < 2; tc++) {
            int n = gs * 256 + hc0 + tc * 16 + l16;
#pragma unroll
            for (int kt = 0; kt < 8; kt++)
                bf[gs][tc][kt] = *(const f16x8*)&whh16[(size_t)n * 256 + kt * 32 + quad * 8];
        }
    float bhn[2];
#pragma unroll
    for (int tc = 0; tc < 2; tc++) bhn[tc] = b_hh[512 + hc0 + tc * 16 + l16];
    float hm[2][4];
#pragma unroll
    for (int tc = 0; tc < 2; tc++)
#pragma unroll
        for (int rr = 0; rr < 4; rr++) hm[tc][rr] = 0.f;
    __syncthreads();

    for (int t = 0; t < 31; t++) {
        // prefetch gi for this step (consumed after MFMA phase; latency hidden)
        float gv[3][2][4];
        const float* gbase = gi + (size_t)(t * 128 + b0) * 768;
#pragma unroll
        for (int gs = 0; gs < 3; gs++)
#pragma unroll
            for (int tc = 0; tc < 2; tc++)
#pragma unroll
                for (int rr = 0; rr < 4; rr++)
                    gv[gs][tc][rr] = gbase[(quad * 4 + rr) * 768 + gs * 256 + hc0 + tc * 16 + l16];

        f32x4 acc[3][2];
#pragma unroll
        for (int gs = 0; gs < 3; gs++)
#pragma unroll
            for (int tc = 0; tc < 2; tc++) acc[gs][tc] = (f32x4){0.f, 0.f, 0.f, 0.f};
#pragma unroll
        for (int kt = 0; kt < 8; kt++) {
            f16x8 af = *(const f16x8*)&h16[l16 * 264 + kt * 32 + quad * 8];
#pragma unroll
            for (int gs = 0; gs < 3; gs++)
#pragma unroll
                for (int tc = 0; tc < 2; tc++)
                    acc[gs][tc] = __builtin_amdgcn_mfma_f32_16x16x32_f16(af, bf[gs][tc][kt], acc[gs][tc], 0, 0, 0);
        }
        __syncthreads();   // all h16 reads complete before overwrite
#pragma unroll
        for (int tc = 0; tc < 2; tc++)
#pragma unroll
            for (int rr = 0; rr < 4; rr++) {
                float rg = 1.f / (1.f + expf(-(gv[0][tc][rr] + acc[0][tc][rr])));
                float zg = 1.f / (1.f + expf(-(gv[1][tc][rr] + acc[1][tc][rr])));
                float ng = tanhf(gv[2][tc][rr] + rg * (acc[2][tc][rr] + bhn[tc]));
                float h = (1.f - zg) * ng + zg * hm[tc][rr];
                hm[tc][rr] = h;
                h16[(quad * 4 + rr) * 264 + hc0 + tc * 16 + l16] = (f16)h;
            }
        __syncthreads();
    }
    // output head
#pragma unroll
    for (int tc = 0; tc < 2; tc++)
#pragma unroll
        for (int rr = 0; rr < 4; rr++)
            hf[(quad * 4 + rr) * 257 + hc0 + tc * 16 + l16] = hm[tc][rr];
    __syncthreads();
    if (tid < 160) {
        int r = tid / 10, oc = tid - r * 10;
        float s = b_out[oc];
        for (int k = 0; k < 256; k++) s += hf[r * 257 + k] * W_out[oc * 256 + k];
        out[(b0 + r) * 10 + oc] = 1.f / (1.f + expf(-s));
    }
}

// ---------------------------------------------------------------- launch
extern "C" void kernel_launch(void* const* d_in, const int* in_sizes, int n_in,
                              void* d_out, int out_size, void* d_ws, size_t ws_size,
                              hipStream_t stream) {
    const float* x     = (const float*)d_in[0];
    const float* W_aug = (const float*)d_in[1];
    // d_in[2] = b_aug — cancels in dx, unused
    const float* W_ih  = (const float*)d_in[3];
    const float* W_hh  = (const float*)d_in[4];
    const float* b_ih  = (const float*)d_in[5];
    const float* b_hh  = (const float*)d_in[6];
    const float* W_out = (const float*)d_in[7];
    const float* b_out = (const float*)d_in[8];
    float* out = (float*)d_out;

    char* ws = (char*)d_ws;
    const size_t SIG_BYTES = (size_t)3968 * 2240 * 2;
    const size_t WIH_BYTES = (size_t)768 * 2240 * 2;
    const size_t WHH_BYTES = (size_t)768 * 256 * 2;
    const size_t GI_BYTES  = (size_t)3968 * 768 * 4;
    if (ws_size < SIG_BYTES + WIH_BYTES + WHH_BYTES + GI_BYTES) return;
    f16* sig16 = (f16*)ws;
    f16* wih16 = (f16*)(ws + SIG_BYTES);
    f16* whh16 = (f16*)(ws + SIG_BYTES + WIH_BYTES);
    float* giw = (float*)(ws + SIG_BYTES + WIH_BYTES + WHH_BYTES);

    hipLaunchKernelGGL(conv_kernel, dim3(7488), dim3(256), 0, stream, W_ih, W_hh, wih16, whh16);
    hipLaunchKernelGGL(sig_kernel, dim3(7936), dim3(64), 0, stream, x, W_aug, sig16);
    hipLaunchKernelGGL(gemm_kernel, dim3(6, 31), dim3(256), 0, stream, sig16, wih16, b_ih, b_hh, giw);
    hipLaunchKernelGGL(gru_kernel, dim3(8), dim3(512), 0, stream, giw, whh16, b_hh, W_out, b_out, out);
}

// Round 3
// 290.830 us; speedup vs baseline: 1.2621x; 1.0237x over previous
//
#include <hip/hip_runtime.h>
#include <hip/hip_bf16.h>
#include <stdint.h>

// Problem constants
// B=128 STREAM=512 IN_CH=4 EXTRA=5 GROUPS=2 DEPTH=3 STEP=16 LENGTH=32 RNN=256 OUT=10
// C=10 SIG_C=1110 W=31 F=2220, padded K = 2240, GEMM M = 31*128 = 3968, N = 768
// gi workspace layout: per (t, bb, gru_tid) lane-contiguous 48 floats padded to 52
//   off = ((t*8+bb)*256 + gtid)*52 + gs*16 + tc*4 + rr

typedef _Float16 f16;
typedef f16  f16x8 __attribute__((ext_vector_type(8)));
typedef float f32x4 __attribute__((ext_vector_type(4)));

#define ASYNC16(gp, lp) __builtin_amdgcn_global_load_lds( \
    (const __attribute__((address_space(1))) void*)(gp),  \
    (__attribute__((address_space(3))) void*)(lp), 16, 0, 0)

// ---------------------------------------------------------------- K0: prep = weight conversion + signatures
// blocks [0, 7488): f32->f16 conversion of W_ih (pad K 2220->2240) and W_hh
// blocks [7488, 9472): signature chains, 4 chains per 256-thr block
__global__ __launch_bounds__(256) void prep_kernel(const float* __restrict__ x,
                                                   const float* __restrict__ W_aug,
                                                   const float* __restrict__ Wih,
                                                   const float* __restrict__ Whh,
                                                   f16* __restrict__ sig16,
                                                   f16* __restrict__ wih16,
                                                   f16* __restrict__ whh16) {
    __shared__ float dxs[4][31][10];
    const int tid = threadIdx.x;
    if (blockIdx.x < 7488) {
        int idx = blockIdx.x * 256 + tid;
        const int NIH = 768 * 2240;
        if (idx < NIH) {
            int r = idx / 2240, k = idx - r * 2240;
            wih16[idx] = (f16)(k < 2220 ? Wih[r * 2220 + k] : 0.0f);
        } else {
            int j = idx - NIH;   // < 768*256 always (7488*256 = NIH + 768*256)
            whh16[j] = (f16)Whh[j];
        }
        return;
    }
    // ---- signature part (block-uniform branch; __syncthreads is safe)
    const int sub = tid >> 6, t64 = tid & 63;
    const int cid = ((int)blockIdx.x - 7488) * 4 + sub;   // 0..7935
    const int w = cid % 31;
    const int bg = cid / 31;
    const int b = bg >> 1, g = bg & 1;
    if (t64 < 31) {
        int s = w * 16 + t64;
        const float4 x0 = *(const float4*)(x + ((size_t)b * 512 + s) * 4);
        const float4 x1 = *(const float4*)(x + ((size_t)b * 512 + s + 1) * 4);
        float d0 = x1.x - x0.x, d1 = x1.y - x0.y, d2 = x1.z - x0.z, d3 = x1.w - x0.w;
        dxs[sub][t64][0] = d0; dxs[sub][t64][1] = d1;
        dxs[sub][t64][2] = d2; dxs[sub][t64][3] = d3;
        dxs[sub][t64][4] = 1.0f / 511.0f;
#pragma unroll
        for (int e = 0; e < 5; e++) {
            const float* wa = W_aug + (g * 5 + e) * 4;
            dxs[sub][t64][5 + e] = d0 * wa[0] + d1 * wa[1] + d2 * wa[2] + d3 * wa[3];
        }
    }
    __syncthreads();
    size_t base = ((size_t)(w * 128 + b)) * 2240 + (size_t)g * 1110;
    if (t64 < 50) {
        int p0 = 2 * t64, p1 = p0 + 1;
        int i0 = p0 / 10, j0 = p0 % 10, j1 = j0 + 1;
        float s3a[10], s3b[10];
#pragma unroll
        for (int k = 0; k < 10; k++) { s3a[k] = 0.f; s3b[k] = 0.f; }
        float s2a = 0.f, s2b = 0.f, s1 = 0.f;
        for (int l = 0; l < 31; l++) {
            float dx[10];
#pragma unroll
            for (int c = 0; c < 10; c++) dx[c] = dxs[sub][l][c];
            float t0 = s1 + dx[i0] * (1.0f / 3.0f);
            float a0 = s2a + t0 * (0.5f * dx[j0]);
            float a1 = s2b + t0 * (0.5f * dx[j1]);
#pragma unroll
            for (int k = 0; k < 10; k++) { s3a[k] += a0 * dx[k]; s3b[k] += a1 * dx[k]; }
            float u = s1 + 0.5f * dx[i0];
            s2a += u * dx[j0];
            s2b += u * dx[j1];
            s1 += dx[i0];
        }
        sig16[base + 10 + p0] = (f16)s2a;
        sig16[base + 10 + p1] = (f16)s2b;
#pragma unroll
        for (int k = 0; k < 10; k++) {
            sig16[base + 110 + p0 * 10 + k] = (f16)s3a[k];
            sig16[base + 110 + p1 * 10 + k] = (f16)s3b[k];
        }
    } else if (t64 < 60) {
        int c = t64 - 50;
        float s = 0.f;
        for (int l = 0; l < 31; l++) s += dxs[sub][l][c];
        sig16[base + c] = (f16)s;
    }
    if (g == 1 && t64 < 20)
        sig16[((size_t)(w * 128 + b)) * 2240 + 2220 + t64] = (f16)0.0f;
}

// ---------------------------------------------------------------- K2: gi = sig @ W_ih.T + biases, written in GRU lane order
__global__ __launch_bounds__(256) void gemm_kernel(const f16* __restrict__ A,     // 3968 x 2240
                                                   const f16* __restrict__ Bw,    // 768 x 2240 (W_ih rows)
                                                   const float* __restrict__ bias,
                                                   const float* __restrict__ bhh,
                                                   float* __restrict__ Cout) {    // GRU-ordered, stride 52
    __shared__ __align__(16) f16 As[128 * 32];
    __shared__ __align__(16) f16 Bs[128 * 32];
    const int tid = threadIdx.x, lane = tid & 63, wid = tid >> 6;
    const int wm = wid >> 1, wn = wid & 1;
    const int Mbase = blockIdx.y * 128, Nbase = blockIdx.x * 128;
    const int lr = lane >> 2;
    const int lk = lane & 3;
    const int l16 = lane & 15, quad = lane >> 4;
    f32x4 acc[4][4];
#pragma unroll
    for (int mt = 0; mt < 4; mt++)
#pragma unroll
        for (int nt = 0; nt < 4; nt++) acc[mt][nt] = (f32x4){0.f, 0.f, 0.f, 0.f};

    for (int kt = 0; kt < 70; kt++) {
        const int k0 = kt * 32;
#pragma unroll
        for (int q = 0; q < 2; q++) {
            int r0 = wid * 32 + q * 16;
            const f16* ga = A + (size_t)(Mbase + r0 + lr) * 2240 + k0 + lk * 8;
            ASYNC16(ga, &As[r0 * 32]);
            const f16* gb = Bw + (size_t)(Nbase + r0 + lr) * 2240 + k0 + lk * 8;
            ASYNC16(gb, &Bs[r0 * 32]);
        }
        __syncthreads();
        f16x8 af[4], bf[4];
#pragma unroll
        for (int mt = 0; mt < 4; mt++)
            af[mt] = *(const f16x8*)&As[(wm * 64 + mt * 16 + l16) * 32 + quad * 8];
#pragma unroll
        for (int nt = 0; nt < 4; nt++)
            bf[nt] = *(const f16x8*)&Bs[(wn * 64 + nt * 16 + l16) * 32 + quad * 8];
#pragma unroll
        for (int mt = 0; mt < 4; mt++)
#pragma unroll
            for (int nt = 0; nt < 4; nt++)
                acc[mt][nt] = __builtin_amdgcn_mfma_f32_16x16x32_f16(af[mt], bf[nt], acc[mt][nt], 0, 0, 0);
        __syncthreads();
    }
    // epilogue: scatter into GRU-lane-contiguous layout (stride 52 floats per lane)
    const int t = blockIdx.y;
#pragma unroll
    for (int mt = 0; mt < 4; mt++) {
        const int bbv = wm * 4 + mt;   // batch sub-block 0..7
#pragma unroll
        for (int nt = 0; nt < 4; nt++) {
            int col = Nbase + wn * 64 + nt * 16 + l16;
            float bv = bias[col] + (col < 512 ? bhh[col] : 0.0f);   // fold b_hh into r,z
            int gs = col >> 8, hc = col & 255;
            int gwid = hc >> 6, gtc = (hc >> 4) & 3, gl16 = hc & 15;
            int gtid = gwid * 64 + quad * 16 + gl16;
            size_t off = ((size_t)(t * 8 + bbv) * 256 + gtid) * 52 + gs * 16 + gtc * 4;
            f32x4 v = acc[mt][nt];
            float4 st = make_float4(v[0] + bv, v[1] + bv, v[2] + bv, v[3] + bv);
            *(float4*)(Cout + off) = st;
        }
    }
}

// ---------------------------------------------------------------- K3: GRU scan + output head
// 8 blocks x 256 threads (4 waves, 1 wave/SIMD, 512-VGPR budget).
// Wave wid owns h-cols [wid*64, +64) for all 3 gates; W_hh fragments (96 x f16x8
// = 384 VGPRs) are register-resident for the whole scan. h ping-pongs in LDS
// (one barrier per step). gi slabs prefetched into LDS via global_load_lds.
__global__ __launch_bounds__(256, 1) void gru_kernel(const float* __restrict__ gi,     // GRU-ordered, stride 52
                                                     const f16* __restrict__ whh16,    // 768 x 256
                                                     const float* __restrict__ b_hh,   // 768
                                                     const float* __restrict__ W_out,  // 10 x 256
                                                     const float* __restrict__ b_out,  // 10
                                                     float* __restrict__ out) {        // 128 x 10
    __shared__ __align__(16) f16 hbuf[2][16 * 264];     // ping-pong h, padded stride
    __shared__ __align__(16) float gibuf[2][13312];     // 2 x 53248 B gi slabs
    __shared__ float hf[16 * 257];
    const int tid = threadIdx.x, lane = tid & 63, wid = tid >> 6;   // wid 0..3
    const int quad = lane >> 4, l16 = lane & 15;
    const int bb = blockIdx.x;                                      // 0..7
    const int hc0 = wid * 64;

    for (int i = tid; i < 16 * 264; i += 256) hbuf[1][i] = (f16)0.0f;   // h_{-1} = 0

    // resident W_hh fragments: 3 gates x 4 col-tiles x 8 k-tiles
    f16x8 bf[3][4][8];
#pragma unroll
    for (int gs = 0; gs < 3; gs++)
#pragma unroll
        for (int tc = 0; tc < 4; tc++) {
            int n = gs * 256 + hc0 + tc * 16 + l16;
#pragma unroll
            for (int kt = 0; kt < 8; kt++)
                bf[gs][tc][kt] = *(const f16x8*)&whh16[(size_t)n * 256 + kt * 32 + quad * 8];
        }
    float bhn[4];
#pragma unroll
    for (int tc = 0; tc < 4; tc++) bhn[tc] = b_hh[512 + hc0 + tc * 16 + l16];
    float hm[4][4];
#pragma unroll
    for (int tc = 0; tc < 4; tc++)
#pragma unroll
        for (int rr = 0; rr < 4; rr++) hm[tc][rr] = 0.f;

    // prefetch slab 0
    {
        const float* gsrc = gi + (size_t)bb * 13312;
#pragma unroll
        for (int i = 0; i < 13; i++)
            ASYNC16(gsrc + (wid * 13 + i) * 256 + lane * 4, &gibuf[0][(wid * 13 + i) * 256]);
    }
    __syncthreads();

    for (int t = 0; t < 31; t++) {
        // prefetch next slab (drained by end-of-step barrier ~1000 cyc later)
        {
            int tn = t < 30 ? t + 1 : 30;
            const float* gsrc = gi + (size_t)(tn * 8 + bb) * 13312;
            float* ldst = gibuf[(t + 1) & 1];
#pragma unroll
            for (int i = 0; i < 13; i++)
                ASYNC16(gsrc + (wid * 13 + i) * 256 + lane * 4, &ldst[(wid * 13 + i) * 256]);
        }
        const f16* hsrc = hbuf[(t + 1) & 1];   // holds h_{t-1}
        f32x4 acc[3][4];
#pragma unroll
        for (int gs = 0; gs < 3; gs++)
#pragma unroll
            for (int tc = 0; tc < 4; tc++) acc[gs][tc] = (f32x4){0.f, 0.f, 0.f, 0.f};
#pragma unroll
        for (int kt = 0; kt < 8; kt++) {
            f16x8 af = *(const f16x8*)&hsrc[l16 * 264 + kt * 32 + quad * 8];
#pragma unroll
            for (int gs = 0; gs < 3; gs++)
#pragma unroll
                for (int tc = 0; tc < 4; tc++)
                    acc[gs][tc] = __builtin_amdgcn_mfma_f32_16x16x32_f16(af, bf[gs][tc][kt], acc[gs][tc], 0, 0, 0);
        }
        f16* hdst = hbuf[t & 1];
        const float* gvb = gibuf[t & 1] + tid * 52;
#pragma unroll
        for (int tc = 0; tc < 4; tc++) {
            f32x4 gr = *(const f32x4*)&gvb[0 * 16 + tc * 4];
            f32x4 gz = *(const f32x4*)&gvb[1 * 16 + tc * 4];
            f32x4 gn = *(const f32x4*)&gvb[2 * 16 + tc * 4];
#pragma unroll
            for (int rr = 0; rr < 4; rr++) {
                float rg = 1.f / (1.f + __expf(-(gr[rr] + acc[0][tc][rr])));
                float zg = 1.f / (1.f + __expf(-(gz[rr] + acc[1][tc][rr])));
                float ar = gn[rr] + rg * (acc[2][tc][rr] + bhn[tc]);
                float e2 = __expf(2.f * ar);
                float ng = 1.f - 2.f / (e2 + 1.f);            // tanh(ar)
                float h = (1.f - zg) * ng + zg * hm[tc][rr];
                hm[tc][rr] = h;
                hdst[(quad * 4 + rr) * 264 + hc0 + tc * 16 + l16] = (f16)h;
            }
        }
        __syncthreads();   // single barrier per step (ping-pong buffers)
    }
    // output head
#pragma unroll
    for (int tc = 0; tc < 4; tc++)
#pragma unroll
        for (int rr = 0; rr < 4; rr++)
            hf[(quad * 4 + rr) * 257 + hc0 + tc * 16 + l16] = hm[tc][rr];
    __syncthreads();
    if (tid < 160) {
        int r = tid / 10, oc = tid - r * 10;
        float s = b_out[oc];
        for (int k = 0; k < 256; k++) s += hf[r * 257 + k] * W_out[oc * 256 + k];
        out[(bb * 16 + r) * 10 + oc] = 1.f / (1.f + __expf(-s));
    }
}

// ---------------------------------------------------------------- launch
extern "C" void kernel_launch(void* const* d_in, const int* in_sizes, int n_in,
                              void* d_out, int out_size, void* d_ws, size_t ws_size,
                              hipStream_t stream) {
    const float* x     = (const float*)d_in[0];
    const float* W_aug = (const float*)d_in[1];
    // d_in[2] = b_aug — cancels in dx, unused
    const float* W_ih  = (const float*)d_in[3];
    const float* W_hh  = (const float*)d_in[4];
    const float* b_ih  = (const float*)d_in[5];
    const float* b_hh  = (const float*)d_in[6];
    const float* W_out = (const float*)d_in[7];
    const float* b_out = (const float*)d_in[8];
    float* out = (float*)d_out;

    char* ws = (char*)d_ws;
    const size_t SIG_BYTES = (size_t)3968 * 2240 * 2;            // 17,776,640
    const size_t WIH_BYTES = (size_t)768 * 2240 * 2;             //  3,440,640
    const size_t WHH_BYTES = (size_t)768 * 256 * 2;              //    393,216
    const size_t GI_BYTES  = (size_t)31 * 8 * 256 * 52 * 4;      // 13,205,504
    if (ws_size < SIG_BYTES + WIH_BYTES + WHH_BYTES + GI_BYTES) return;
    f16* sig16 = (f16*)ws;
    f16* wih16 = (f16*)(ws + SIG_BYTES);
    f16* whh16 = (f16*)(ws + SIG_BYTES + WIH_BYTES);
    float* giw = (float*)(ws + SIG_BYTES + WIH_BYTES + WHH_BYTES);

    hipLaunchKernelGGL(prep_kernel, dim3(9472), dim3(256), 0, stream,
                       x, W_aug, W_ih, W_hh, sig16, wih16, whh16);
    hipLaunchKernelGGL(gemm_kernel, dim3(6, 31), dim3(256), 0, stream,
                       sig16, wih16, b_ih, b_hh, giw);
    hipLaunchKernelGGL(gru_kernel, dim3(8), dim3(256), 0, stream,
                       giw, whh16, b_hh, W_out, b_out, out);
}

// Round 4
// 271.046 us; speedup vs baseline: 1.3542x; 1.0730x over previous
//
#include <hip/hip_runtime.h>
#include <hip/hip_bf16.h>
#include <stdint.h>

// Problem constants
// B=128 STREAM=512 IN_CH=4 EXTRA=5 GROUPS=2 DEPTH=3 STEP=16 LENGTH=32 RNN=256 OUT=10
// C=10 SIG_C=1110 W=31 F=2220, padded K = 2240, GEMM M = 31*128 = 3968, N = 768
// gi layout: per (t, bb, glane) 12 contiguous floats:
//   off = ((t*8+bb)*1024 + wid*64 + quad*16 + l16)*12 + gs*4 + rr
//   meaning gi[t][row = bb*16 + quad*4 + rr][col = gs*256 + wid*16 + l16]

typedef _Float16 f16;
typedef f16  f16x8 __attribute__((ext_vector_type(8)));
typedef float f32x4 __attribute__((ext_vector_type(4)));

#define ASYNC16(gp, lp) __builtin_amdgcn_global_load_lds( \
    (const __attribute__((address_space(1))) void*)(gp),  \
    (__attribute__((address_space(3))) void*)(lp), 16, 0, 0)

// barrier that drains LDS only (keeps global register-prefetch loads in flight;
// safe because all global loads here land in private registers)
#define BAR_LDS() do { asm volatile("s_waitcnt lgkmcnt(0)" ::: "memory"); \
                       __builtin_amdgcn_s_barrier();                      \
                       asm volatile("" ::: "memory"); } while (0)

// ---------------------------------------------------------------- K0: prep = weight conversion + signatures
__global__ __launch_bounds__(256) void prep_kernel(const float* __restrict__ x,
                                                   const float* __restrict__ W_aug,
                                                   const float* __restrict__ Wih,
                                                   const float* __restrict__ Whh,
                                                   f16* __restrict__ sig16,
                                                   f16* __restrict__ wih16,
                                                   f16* __restrict__ whh16) {
    __shared__ float dxs[4][31][10];
    const int tid = threadIdx.x;
    if (blockIdx.x < 7488) {
        int idx = blockIdx.x * 256 + tid;
        const int NIH = 768 * 2240;
        if (idx < NIH) {
            int r = idx / 2240, k = idx - r * 2240;
            wih16[idx] = (f16)(k < 2220 ? Wih[r * 2220 + k] : 0.0f);
        } else {
            int j = idx - NIH;
            whh16[j] = (f16)Whh[j];
        }
        return;
    }
    const int sub = tid >> 6, t64 = tid & 63;
    const int cid = ((int)blockIdx.x - 7488) * 4 + sub;   // 0..7935
    const int w = cid % 31;
    const int bg = cid / 31;
    const int b = bg >> 1, g = bg & 1;
    if (t64 < 31) {
        int s = w * 16 + t64;
        const float4 x0 = *(const float4*)(x + ((size_t)b * 512 + s) * 4);
        const float4 x1 = *(const float4*)(x + ((size_t)b * 512 + s + 1) * 4);
        float d0 = x1.x - x0.x, d1 = x1.y - x0.y, d2 = x1.z - x0.z, d3 = x1.w - x0.w;
        dxs[sub][t64][0] = d0; dxs[sub][t64][1] = d1;
        dxs[sub][t64][2] = d2; dxs[sub][t64][3] = d3;
        dxs[sub][t64][4] = 1.0f / 511.0f;
#pragma unroll
        for (int e = 0; e < 5; e++) {
            const float* wa = W_aug + (g * 5 + e) * 4;
            dxs[sub][t64][5 + e] = d0 * wa[0] + d1 * wa[1] + d2 * wa[2] + d3 * wa[3];
        }
    }
    __syncthreads();
    size_t base = ((size_t)(w * 128 + b)) * 2240 + (size_t)g * 1110;
    if (t64 < 50) {
        int p0 = 2 * t64, p1 = p0 + 1;
        int i0 = p0 / 10, j0 = p0 % 10, j1 = j0 + 1;
        float s3a[10], s3b[10];
#pragma unroll
        for (int k = 0; k < 10; k++) { s3a[k] = 0.f; s3b[k] = 0.f; }
        float s2a = 0.f, s2b = 0.f, s1 = 0.f;
        for (int l = 0; l < 31; l++) {
            float dx[10];
#pragma unroll
            for (int c = 0; c < 10; c++) dx[c] = dxs[sub][l][c];
            float t0 = s1 + dx[i0] * (1.0f / 3.0f);
            float a0 = s2a + t0 * (0.5f * dx[j0]);
            float a1 = s2b + t0 * (0.5f * dx[j1]);
#pragma unroll
            for (int k = 0; k < 10; k++) { s3a[k] += a0 * dx[k]; s3b[k] += a1 * dx[k]; }
            float u = s1 + 0.5f * dx[i0];
            s2a += u * dx[j0];
            s2b += u * dx[j1];
            s1 += dx[i0];
        }
        sig16[base + 10 + p0] = (f16)s2a;
        sig16[base + 10 + p1] = (f16)s2b;
#pragma unroll
        for (int k = 0; k < 10; k++) {
            sig16[base + 110 + p0 * 10 + k] = (f16)s3a[k];
            sig16[base + 110 + p1 * 10 + k] = (f16)s3b[k];
        }
    } else if (t64 < 60) {
        int c = t64 - 50;
        float s = 0.f;
        for (int l = 0; l < 31; l++) s += dxs[sub][l][c];
        sig16[base + c] = (f16)s;
    }
    if (g == 1 && t64 < 20)
        sig16[((size_t)(w * 128 + b)) * 2240 + 2220 + t64] = (f16)0.0f;
}

// ---------------------------------------------------------------- K2: gi = sig @ W_ih.T + biases, GRU-lane-contiguous output
__global__ __launch_bounds__(256) void gemm_kernel(const f16* __restrict__ A,     // 3968 x 2240
                                                   const f16* __restrict__ Bw,    // 768 x 2240
                                                   const float* __restrict__ bias,
                                                   const float* __restrict__ bhh,
                                                   float* __restrict__ Cout) {    // GRU-ordered, 12 floats/lane
    __shared__ __align__(16) f16 As[128 * 32];
    __shared__ __align__(16) f16 Bs[128 * 32];
    const int tid = threadIdx.x, lane = tid & 63, wid = tid >> 6;
    const int wm = wid >> 1, wn = wid & 1;
    const int Mbase = blockIdx.y * 128, Nbase = blockIdx.x * 128;
    const int lr = lane >> 2;
    const int lk = lane & 3;
    const int l16 = lane & 15, quad = lane >> 4;
    f32x4 acc[4][4];
#pragma unroll
    for (int mt = 0; mt < 4; mt++)
#pragma unroll
        for (int nt = 0; nt < 4; nt++) acc[mt][nt] = (f32x4){0.f, 0.f, 0.f, 0.f};

    for (int kt = 0; kt < 70; kt++) {
        const int k0 = kt * 32;
#pragma unroll
        for (int q = 0; q < 2; q++) {
            int r0 = wid * 32 + q * 16;
            const f16* ga = A + (size_t)(Mbase + r0 + lr) * 2240 + k0 + lk * 8;
            ASYNC16(ga, &As[r0 * 32]);
            const f16* gb = Bw + (size_t)(Nbase + r0 + lr) * 2240 + k0 + lk * 8;
            ASYNC16(gb, &Bs[r0 * 32]);
        }
        __syncthreads();
        f16x8 af[4], bf[4];
#pragma unroll
        for (int mt = 0; mt < 4; mt++)
            af[mt] = *(const f16x8*)&As[(wm * 64 + mt * 16 + l16) * 32 + quad * 8];
#pragma unroll
        for (int nt = 0; nt < 4; nt++)
            bf[nt] = *(const f16x8*)&Bs[(wn * 64 + nt * 16 + l16) * 32 + quad * 8];
#pragma unroll
        for (int mt = 0; mt < 4; mt++)
#pragma unroll
            for (int nt = 0; nt < 4; nt++)
                acc[mt][nt] = __builtin_amdgcn_mfma_f32_16x16x32_f16(af[mt], bf[nt], acc[mt][nt], 0, 0, 0);
        __syncthreads();
    }
    // epilogue: scatter into GRU layout (12 contiguous floats per target lane)
    const int t = blockIdx.y;
#pragma unroll
    for (int mt = 0; mt < 4; mt++) {
        const int bbv = wm * 4 + mt;   // batch sub-block 0..7
#pragma unroll
        for (int nt = 0; nt < 4; nt++) {
            int col = Nbase + wn * 64 + nt * 16 + l16;
            float bv = bias[col] + (col < 512 ? bhh[col] : 0.0f);   // fold b_hh into r,z
            int gs = col >> 8, hc = col & 255;
            int gw = hc >> 4, gl = hc & 15;
            int glane = gw * 64 + quad * 16 + gl;
            size_t off = ((size_t)(t * 8 + bbv) * 1024 + glane) * 12 + gs * 4;
            f32x4 v = acc[mt][nt];
            float4 st = make_float4(v[0] + bv, v[1] + bv, v[2] + bv, v[3] + bv);
            *(float4*)(Cout + off) = st;
        }
    }
}

// ---------------------------------------------------------------- K3: GRU scan + output head
// 8 blocks x 1024 threads (16 waves, 4/SIMD). Wave wid owns h-cols
// [wid*16, wid*16+16) for all 3 gates: 24 resident B-fragments = 96 VGPRs
// (fits the 256 arch-VGPR cap with room; no per-step W_hh re-stream).
// h ping-pongs in LDS; gi register-prefetched one step ahead; barrier drains
// LDS only so the prefetch stays in flight.
__global__ __launch_bounds__(1024, 1) void gru_kernel(const float* __restrict__ gi,   // GRU-ordered, 12 f/lane
                                                      const f16* __restrict__ whh16,  // 768 x 256
                                                      const float* __restrict__ b_hh, // 768
                                                      const float* __restrict__ W_out,// 10 x 256
                                                      const float* __restrict__ b_out,// 10
                                                      float* __restrict__ out) {      // 128 x 10
    __shared__ __align__(16) f16 hbuf[2][16 * 264];
    __shared__ float hf[16 * 257];
    const int tid = threadIdx.x, lane = tid & 63, wid = tid >> 6;   // wid 0..15
    const int quad = lane >> 4, l16 = lane & 15;
    const int bb = blockIdx.x;                                      // 0..7
    const int hc = wid * 16 + l16;                                  // owned h-column

    for (int i = tid; i < 16 * 264; i += 1024) hbuf[1][i] = (f16)0.0f;   // h_{-1} = 0

    // resident W_hh fragments: 3 gates x 8 k-tiles (96 VGPRs)
    f16x8 bf[3][8];
#pragma unroll
    for (int gs = 0; gs < 3; gs++) {
        const f16* wsrc = whh16 + (size_t)(gs * 256 + hc) * 256;
#pragma unroll
        for (int kt = 0; kt < 8; kt++)
            bf[gs][kt] = *(const f16x8*)&wsrc[kt * 32 + quad * 8];
    }
    const float bhn = b_hh[512 + hc];
    float hm[4];
#pragma unroll
    for (int rr = 0; rr < 4; rr++) hm[rr] = 0.f;

    // prefetch gi for t=0
    const size_t lanebase = ((size_t)bb * 1024 + wid * 64 + quad * 16 + l16) * 12;
    f32x4 gv[3];
#pragma unroll
    for (int gs = 0; gs < 3; gs++)
        gv[gs] = *(const f32x4*)(gi + lanebase + gs * 4);

    BAR_LDS();

    for (int t = 0; t < 31; t++) {
        // prefetch gi for t+1 (registers; survives the LDS-only barrier)
        f32x4 gvn[3];
        {
            int tn = t < 30 ? t + 1 : 30;
            const float* gsrc = gi + (size_t)tn * 8 * 1024 * 12 + lanebase;
#pragma unroll
            for (int gs = 0; gs < 3; gs++)
                gvn[gs] = *(const f32x4*)(gsrc + gs * 4);
        }
        const f16* hsrc = hbuf[(t + 1) & 1];   // h_{t-1}
        f32x4 acc[3];
#pragma unroll
        for (int gs = 0; gs < 3; gs++) acc[gs] = (f32x4){0.f, 0.f, 0.f, 0.f};
#pragma unroll
        for (int kt = 0; kt < 8; kt++) {
            f16x8 af = *(const f16x8*)&hsrc[l16 * 264 + kt * 32 + quad * 8];
#pragma unroll
            for (int gs = 0; gs < 3; gs++)
                acc[gs] = __builtin_amdgcn_mfma_f32_16x16x32_f16(af, bf[gs][kt], acc[gs], 0, 0, 0);
        }
        f16* hdst = hbuf[t & 1];
#pragma unroll
        for (int rr = 0; rr < 4; rr++) {
            float rg = 1.f / (1.f + __expf(-(gv[0][rr] + acc[0][rr])));
            float zg = 1.f / (1.f + __expf(-(gv[1][rr] + acc[1][rr])));
            float ar = gv[2][rr] + rg * (acc[2][rr] + bhn);
            float e2 = __expf(2.f * ar);
            float ng = 1.f - 2.f / (e2 + 1.f);            // tanh(ar)
            float h = (1.f - zg) * ng + zg * hm[rr];
            hm[rr] = h;
            hdst[(quad * 4 + rr) * 264 + hc] = (f16)h;
        }
#pragma unroll
        for (int gs = 0; gs < 3; gs++) gv[gs] = gvn[gs];
        BAR_LDS();   // LDS-only drain; gi prefetch stays in flight
    }
    // output head
#pragma unroll
    for (int rr = 0; rr < 4; rr++)
        hf[(quad * 4 + rr) * 257 + hc] = hm[rr];
    BAR_LDS();
    if (tid < 160) {
        int r = tid / 10, oc = tid - r * 10;
        float s = b_out[oc];
        for (int k = 0; k < 256; k++) s += hf[r * 257 + k] * W_out[oc * 256 + k];
        out[(bb * 16 + r) * 10 + oc] = 1.f / (1.f + __expf(-s));
    }
}

// ---------------------------------------------------------------- launch
extern "C" void kernel_launch(void* const* d_in, const int* in_sizes, int n_in,
                              void* d_out, int out_size, void* d_ws, size_t ws_size,
                              hipStream_t stream) {
    const float* x     = (const float*)d_in[0];
    const float* W_aug = (const float*)d_in[1];
    // d_in[2] = b_aug — cancels in dx, unused
    const float* W_ih  = (const float*)d_in[3];
    const float* W_hh  = (const float*)d_in[4];
    const float* b_ih  = (const float*)d_in[5];
    const float* b_hh  = (const float*)d_in[6];
    const float* W_out = (const float*)d_in[7];
    const float* b_out = (const float*)d_in[8];
    float* out = (float*)d_out;

    char* ws = (char*)d_ws;
    const size_t SIG_BYTES = (size_t)3968 * 2240 * 2;            // 17,776,640
    const size_t WIH_BYTES = (size_t)768 * 2240 * 2;             //  3,440,640
    const size_t WHH_BYTES = (size_t)768 * 256 * 2;              //    393,216
    const size_t GI_BYTES  = (size_t)31 * 8 * 1024 * 12 * 4;     // 12,189,696
    if (ws_size < SIG_BYTES + WIH_BYTES + WHH_BYTES + GI_BYTES) return;
    f16* sig16 = (f16*)ws;
    f16* wih16 = (f16*)(ws + SIG_BYTES);
    f16* whh16 = (f16*)(ws + SIG_BYTES + WIH_BYTES);
    float* giw = (float*)(ws + SIG_BYTES + WIH_BYTES + WHH_BYTES);

    hipLaunchKernelGGL(prep_kernel, dim3(9472), dim3(256), 0, stream,
                       x, W_aug, W_ih, W_hh, sig16, wih16, whh16);
    hipLaunchKernelGGL(gemm_kernel, dim3(6, 31), dim3(256), 0, stream,
                       sig16, wih16, b_ih, b_hh, giw);
    hipLaunchKernelGGL(gru_kernel, dim3(8), dim3(1024), 0, stream,
                       giw, whh16, b_hh, W_out, b_out, out);
}

// Round 5
// 258.218 us; speedup vs baseline: 1.4215x; 1.0497x over previous
//
#include <hip/hip_runtime.h>
#include <hip/hip_bf16.h>
#include <stdint.h>

// Problem constants
// B=128 STREAM=512 IN_CH=4 EXTRA=5 GROUPS=2 DEPTH=3 STEP=16 LENGTH=32 RNN=256 OUT=10
// C=10 SIG_C=1110 W=31 F=2220, padded K = 2240, GEMM M = 31*128 = 3968, N = 768
// gi layout: per (t, bb, glane) 12 contiguous floats:
//   off = ((t*8+bb)*1024 + glane)*12 + gs*4 + rr
//   where glane = wid*64 + quad*16 + l16 handles row = bb*16+quad*4+rr, col = gs*256 + wid*16 + l16

typedef _Float16 f16;
typedef f16  f16x8 __attribute__((ext_vector_type(8)));
typedef float f32x4 __attribute__((ext_vector_type(4)));

#define ASYNC16(gp, lp) __builtin_amdgcn_global_load_lds( \
    (const __attribute__((address_space(1))) void*)(gp),  \
    (__attribute__((address_space(3))) void*)(lp), 16, 0, 0)

// barrier that drains LDS only (global register-prefetch loads stay in flight;
// safe because all global loads land in private registers)
#define BAR_LDS() do { asm volatile("s_waitcnt lgkmcnt(0)" ::: "memory"); \
                       __builtin_amdgcn_s_barrier();                      \
                       asm volatile("" ::: "memory"); } while (0)

// ---------------------------------------------------------------- K0: prep = weight conversion + signatures
__global__ __launch_bounds__(256) void prep_kernel(const float* __restrict__ x,
                                                   const float* __restrict__ W_aug,
                                                   const float* __restrict__ Wih,
                                                   const float* __restrict__ Whh,
                                                   f16* __restrict__ sig16,
                                                   f16* __restrict__ wih16,
                                                   f16* __restrict__ whh16) {
    __shared__ float dxs[4][31][10];
    const int tid = threadIdx.x;
    if (blockIdx.x < 7488) {
        int idx = blockIdx.x * 256 + tid;
        const int NIH = 768 * 2240;
        if (idx < NIH) {
            int r = idx / 2240, k = idx - r * 2240;
            wih16[idx] = (f16)(k < 2220 ? Wih[r * 2220 + k] : 0.0f);
        } else {
            int j = idx - NIH;
            whh16[j] = (f16)Whh[j];
        }
        return;
    }
    const int sub = tid >> 6, t64 = tid & 63;
    const int cid = ((int)blockIdx.x - 7488) * 4 + sub;   // 0..7935
    const int w = cid % 31;
    const int bg = cid / 31;
    const int b = bg >> 1, g = bg & 1;
    if (t64 < 31) {
        int s = w * 16 + t64;
        const float4 x0 = *(const float4*)(x + ((size_t)b * 512 + s) * 4);
        const float4 x1 = *(const float4*)(x + ((size_t)b * 512 + s + 1) * 4);
        float d0 = x1.x - x0.x, d1 = x1.y - x0.y, d2 = x1.z - x0.z, d3 = x1.w - x0.w;
        dxs[sub][t64][0] = d0; dxs[sub][t64][1] = d1;
        dxs[sub][t64][2] = d2; dxs[sub][t64][3] = d3;
        dxs[sub][t64][4] = 1.0f / 511.0f;
#pragma unroll
        for (int e = 0; e < 5; e++) {
            const float* wa = W_aug + (g * 5 + e) * 4;
            dxs[sub][t64][5 + e] = d0 * wa[0] + d1 * wa[1] + d2 * wa[2] + d3 * wa[3];
        }
    }
    __syncthreads();
    size_t base = ((size_t)(w * 128 + b)) * 2240 + (size_t)g * 1110;
    if (t64 < 50) {
        int p0 = 2 * t64, p1 = p0 + 1;
        int i0 = p0 / 10, j0 = p0 % 10, j1 = j0 + 1;
        float s3a[10], s3b[10];
#pragma unroll
        for (int k = 0; k < 10; k++) { s3a[k] = 0.f; s3b[k] = 0.f; }
        float s2a = 0.f, s2b = 0.f, s1 = 0.f;
        for (int l = 0; l < 31; l++) {
            float dx[10];
#pragma unroll
            for (int c = 0; c < 10; c++) dx[c] = dxs[sub][l][c];
            float t0 = s1 + dx[i0] * (1.0f / 3.0f);
            float a0 = s2a + t0 * (0.5f * dx[j0]);
            float a1 = s2b + t0 * (0.5f * dx[j1]);
#pragma unroll
            for (int k = 0; k < 10; k++) { s3a[k] += a0 * dx[k]; s3b[k] += a1 * dx[k]; }
            float u = s1 + 0.5f * dx[i0];
            s2a += u * dx[j0];
            s2b += u * dx[j1];
            s1 += dx[i0];
        }
        sig16[base + 10 + p0] = (f16)s2a;
        sig16[base + 10 + p1] = (f16)s2b;
#pragma unroll
        for (int k = 0; k < 10; k++) {
            sig16[base + 110 + p0 * 10 + k] = (f16)s3a[k];
            sig16[base + 110 + p1 * 10 + k] = (f16)s3b[k];
        }
    } else if (t64 < 60) {
        int c = t64 - 50;
        float s = 0.f;
        for (int l = 0; l < 31; l++) s += dxs[sub][l][c];
        sig16[base + c] = (f16)s;
    }
    if (g == 1 && t64 < 20)
        sig16[((size_t)(w * 128 + b)) * 2240 + 2220 + t64] = (f16)0.0f;
}

// ---------------------------------------------------------------- K2: gi = sig @ W_ih.T + biases, GRU-lane-contiguous output
__global__ __launch_bounds__(256) void gemm_kernel(const f16* __restrict__ A,     // 3968 x 2240
                                                   const f16* __restrict__ Bw,    // 768 x 2240
                                                   const float* __restrict__ bias,
                                                   const float* __restrict__ bhh,
                                                   float* __restrict__ Cout) {    // GRU-ordered, 12 floats/lane
    __shared__ __align__(16) f16 As[128 * 32];
    __shared__ __align__(16) f16 Bs[128 * 32];
    const int tid = threadIdx.x, lane = tid & 63, wid = tid >> 6;
    const int wm = wid >> 1, wn = wid & 1;
    const int Mbase = blockIdx.y * 128, Nbase = blockIdx.x * 128;
    const int lr = lane >> 2;
    const int lk = lane & 3;
    const int l16 = lane & 15, quad = lane >> 4;
    f32x4 acc[4][4];
#pragma unroll
    for (int mt = 0; mt < 4; mt++)
#pragma unroll
        for (int nt = 0; nt < 4; nt++) acc[mt][nt] = (f32x4){0.f, 0.f, 0.f, 0.f};

    for (int kt = 0; kt < 70; kt++) {
        const int k0 = kt * 32;
#pragma unroll
        for (int q = 0; q < 2; q++) {
            int r0 = wid * 32 + q * 16;
            const f16* ga = A + (size_t)(Mbase + r0 + lr) * 2240 + k0 + lk * 8;
            ASYNC16(ga, &As[r0 * 32]);
            const f16* gb = Bw + (size_t)(Nbase + r0 + lr) * 2240 + k0 + lk * 8;
            ASYNC16(gb, &Bs[r0 * 32]);
        }
        __syncthreads();
        f16x8 af[4], bf[4];
#pragma unroll
        for (int mt = 0; mt < 4; mt++)
            af[mt] = *(const f16x8*)&As[(wm * 64 + mt * 16 + l16) * 32 + quad * 8];
#pragma unroll
        for (int nt = 0; nt < 4; nt++)
            bf[nt] = *(const f16x8*)&Bs[(wn * 64 + nt * 16 + l16) * 32 + quad * 8];
#pragma unroll
        for (int mt = 0; mt < 4; mt++)
#pragma unroll
            for (int nt = 0; nt < 4; nt++)
                acc[mt][nt] = __builtin_amdgcn_mfma_f32_16x16x32_f16(af[mt], bf[nt], acc[mt][nt], 0, 0, 0);
        __syncthreads();
    }
    // epilogue: scatter into GRU layout (12 contiguous floats per target lane)
    const int t = blockIdx.y;
#pragma unroll
    for (int mt = 0; mt < 4; mt++) {
        const int bbv = wm * 4 + mt;   // batch sub-block 0..7
#pragma unroll
        for (int nt = 0; nt < 4; nt++) {
            int col = Nbase + wn * 64 + nt * 16 + l16;
            float bv = bias[col] + (col < 512 ? bhh[col] : 0.0f);   // fold b_hh into r,z
            int gs = col >> 8, hc = col & 255;
            int gw = hc >> 4, gl = hc & 15;
            int glane = gw * 64 + quad * 16 + gl;
            size_t off = ((size_t)(t * 8 + bbv) * 1024 + glane) * 12 + gs * 4;
            f32x4 v = acc[mt][nt];
            float4 st = make_float4(v[0] + bv, v[1] + bv, v[2] + bv, v[3] + bv);
            *(float4*)(Cout + off) = st;
        }
    }
}

// ---------------------------------------------------------------- K3: GRU scan + output head
// 8 blocks x 1024 threads (16 waves, 4/SIMD, 128-VGPR cap stated via launch_bounds).
// Wave wid owns h-cols [wid*16,+16) x 3 gates: 24 B-fragments = 96 VGPRs,
// pinned resident via asm-opacity (cannot be rematerialized). h master lives in
// LDS as f16 (no hm registers); gi register-prefetched one step ahead; barriers
// drain LDS only.
__global__ __launch_bounds__(1024, 4) void gru_kernel(const float* __restrict__ gi,   // GRU-ordered, 12 f/lane
                                                      const f16* __restrict__ whh16,  // 768 x 256
                                                      const float* __restrict__ b_hh, // 768
                                                      const float* __restrict__ W_out,// 10 x 256
                                                      const float* __restrict__ b_out,// 10
                                                      float* __restrict__ out) {      // 128 x 10
    __shared__ __align__(16) f16 hbuf[2][16 * 264];
    const int tid = threadIdx.x, lane = tid & 63, wid = tid >> 6;   // wid 0..15
    const int quad = lane >> 4, l16 = lane & 15;
    const int bb = blockIdx.x;                                      // 0..7
    const int hc = wid * 16 + l16;                                  // owned h-column

    for (int i = tid; i < 16 * 264; i += 1024) hbuf[1][i] = (f16)0.0f;   // h_{-1} = 0

    // resident W_hh fragments: 3 gates x 8 k-tiles, stored as f32x4, pinned
    f32x4 bf[3][8];
#pragma unroll
    for (int gs = 0; gs < 3; gs++) {
        const f16* wsrc = whh16 + (size_t)(gs * 256 + hc) * 256;
#pragma unroll
        for (int kt = 0; kt < 8; kt++)
            bf[gs][kt] = *(const f32x4*)&wsrc[kt * 32 + quad * 8];
    }
#pragma unroll
    for (int gs = 0; gs < 3; gs++)
#pragma unroll
        for (int kt = 0; kt < 8; kt++)
            asm volatile("" : "+v"(bf[gs][kt]));   // opaque: forces residency

    const float bhn = b_hh[512 + hc];
    const size_t lanebase = ((size_t)bb * 1024 + tid) * 12;

    // prefetch gi for t=0
    f32x4 gv[3];
#pragma unroll
    for (int gs = 0; gs < 3; gs++)
        gv[gs] = *(const f32x4*)(gi + lanebase + gs * 4);

    BAR_LDS();

    for (int t = 0; t < 31; t++) {
        const f16* hsrc = hbuf[(t + 1) & 1];   // h_{t-1}
        f16* hdst = hbuf[t & 1];
        f32x4 acc[3];
#pragma unroll
        for (int gs = 0; gs < 3; gs++) acc[gs] = (f32x4){0.f, 0.f, 0.f, 0.f};
#pragma unroll
        for (int kt = 0; kt < 8; kt++) {
            f16x8 af = *(const f16x8*)&hsrc[l16 * 264 + kt * 32 + quad * 8];
#pragma unroll
            for (int gs = 0; gs < 3; gs++)
                acc[gs] = __builtin_amdgcn_mfma_f32_16x16x32_f16(
                    af, __builtin_bit_cast(f16x8, bf[gs][kt]), acc[gs], 0, 0, 0);
        }
#pragma unroll
        for (int rr = 0; rr < 4; rr++) {
            float hmv = (float)hsrc[(quad * 4 + rr) * 264 + hc];   // h_{t-1} own value
            float rg = 1.f / (1.f + __expf(-(gv[0][rr] + acc[0][rr])));
            float zg = 1.f / (1.f + __expf(-(gv[1][rr] + acc[1][rr])));
            float ar = gv[2][rr] + rg * (acc[2][rr] + bhn);
            float e2 = __expf(2.f * ar);
            float ng = 1.f - 2.f / (e2 + 1.f);            // tanh(ar)
            float h = fmaf(zg, hmv - ng, ng);             // (1-z)n + z*hm
            hdst[(quad * 4 + rr) * 264 + hc] = (f16)h;
        }
        // prefetch gi for t+1 (registers; survives the LDS-only barrier)
        {
            int tn = t < 30 ? t + 1 : 30;
            const float* gsrc = gi + (size_t)tn * 98304 + lanebase;
#pragma unroll
            for (int gs = 0; gs < 3; gs++)
                gv[gs] = *(const f32x4*)(gsrc + gs * 4);
        }
        BAR_LDS();   // orders hbuf only; gi loads stay in flight
    }
    // output head: final h is in hbuf[0] (t=30 wrote hbuf[30&1])
    if (tid < 160) {
        int r = tid / 10, oc = tid - r * 10;
        const f16* hfin = hbuf[0];
        float s = b_out[oc];
        for (int k = 0; k < 256; k++) s += (float)hfin[r * 264 + k] * W_out[oc * 256 + k];
        out[(bb * 16 + r) * 10 + oc] = 1.f / (1.f + __expf(-s));
    }
}

// ---------------------------------------------------------------- launch
extern "C" void kernel_launch(void* const* d_in, const int* in_sizes, int n_in,
                              void* d_out, int out_size, void* d_ws, size_t ws_size,
                              hipStream_t stream) {
    const float* x     = (const float*)d_in[0];
    const float* W_aug = (const float*)d_in[1];
    // d_in[2] = b_aug — cancels in dx, unused
    const float* W_ih  = (const float*)d_in[3];
    const float* W_hh  = (const float*)d_in[4];
    const float* b_ih  = (const float*)d_in[5];
    const float* b_hh  = (const float*)d_in[6];
    const float* W_out = (const float*)d_in[7];
    const float* b_out = (const float*)d_in[8];
    float* out = (float*)d_out;

    char* ws = (char*)d_ws;
    const size_t SIG_BYTES = (size_t)3968 * 2240 * 2;            // 17,776,640
    const size_t WIH_BYTES = (size_t)768 * 2240 * 2;             //  3,440,640
    const size_t WHH_BYTES = (size_t)768 * 256 * 2;              //    393,216
    const size_t GI_BYTES  = (size_t)31 * 8 * 1024 * 12 * 4;     // 12,189,696
    if (ws_size < SIG_BYTES + WIH_BYTES + WHH_BYTES + GI_BYTES) return;
    f16* sig16 = (f16*)ws;
    f16* wih16 = (f16*)(ws + SIG_BYTES);
    f16* whh16 = (f16*)(ws + SIG_BYTES + WIH_BYTES);
    float* giw = (float*)(ws + SIG_BYTES + WIH_BYTES + WHH_BYTES);

    hipLaunchKernelGGL(prep_kernel, dim3(9472), dim3(256), 0, stream,
                       x, W_aug, W_ih, W_hh, sig16, wih16, whh16);
    hipLaunchKernelGGL(gemm_kernel, dim3(6, 31), dim3(256), 0, stream,
                       sig16, wih16, b_ih, b_hh, giw);
    hipLaunchKernelGGL(gru_kernel, dim3(8), dim3(1024), 0, stream,
                       giw, whh16, b_hh, W_out, b_out, out);
}

// Round 7
// 244.061 us; speedup vs baseline: 1.5039x; 1.0580x over previous
//
#include <hip/hip_runtime.h>
#include <hip/hip_bf16.h>
#include <stdint.h>

// Problem constants
// B=128 STREAM=512 IN_CH=4 EXTRA=5 GROUPS=2 DEPTH=3 STEP=16 LENGTH=32 RNN=256 OUT=10
// C=10 SIG_C=1110 W=31 F=2220, padded K = 2240, GEMM M = 31*128 = 3968, N = 768
// gi layout (f16): per (t, bb, tid) 24 contiguous f16:
//   off = ((t*8+bb)*512 + tid)*24 + (gs*2+tc)*4 + rr
//   row = bb*16 + quad*4 + rr, col = gs*256 + wid*32 + tc*16 + l16, tid = wid*64+quad*16+l16
// GRU: r,z gates in fp8 e4m3 (W_hh*16), n gate in f16. W_hh pinned in a[0:127],
// acc in a[128:151] -> 152 AGPRs, ~104 VGPRs left (fits 256/wave at 512 thr).

typedef _Float16 f16;
typedef f16  f16x4 __attribute__((ext_vector_type(4)));
typedef f16  f16x8 __attribute__((ext_vector_type(8)));
typedef float f32x2 __attribute__((ext_vector_type(2)));
typedef float f32x4 __attribute__((ext_vector_type(4)));

#define ASYNC16(gp, lp) __builtin_amdgcn_global_load_lds( \
    (const __attribute__((address_space(1))) void*)(gp),  \
    (__attribute__((address_space(3))) void*)(lp), 16, 0, 0)

#define BAR_LDS() do { asm volatile("s_waitcnt lgkmcnt(0)" ::: "memory"); \
                       __builtin_amdgcn_s_barrier();                      \
                       asm volatile("" ::: "memory"); } while (0)

// ---------------------------------------------------------------- K0: prep
// blocks [0,8000): convert W_ih->f16 (pad 2220->2240), W_hh->f16, W_hh[rz]*16->fp8
// blocks [8000,9984): signature chains, 4 per block
__global__ __launch_bounds__(256) void prep_kernel(const float* __restrict__ x,
                                                   const float* __restrict__ W_aug,
                                                   const float* __restrict__ Wih,
                                                   const float* __restrict__ Whh,
                                                   f16* __restrict__ sig16,
                                                   f16* __restrict__ wih16,
                                                   f16* __restrict__ whh16,
                                                   uint8_t* __restrict__ whh8) {
    __shared__ float dxs[4][31][10];
    const int tid = threadIdx.x;
    if (blockIdx.x < 8000) {
        int idx = blockIdx.x * 256 + tid;
        const int NIH = 768 * 2240;          // 1,720,320
        const int N2  = 768 * 256;           //   196,608
        if (idx < NIH) {
            int r = idx / 2240, k = idx - r * 2240;
            wih16[idx] = (f16)(k < 2220 ? Wih[r * 2220 + k] : 0.0f);
        } else if (idx < NIH + N2) {
            int j = idx - NIH;
            whh16[j] = (f16)Whh[j];
        } else {
            int j2 = idx - NIH - N2;         // < 512*256: r,z gate rows
            int pk = __builtin_amdgcn_cvt_pk_fp8_f32(Whh[j2] * 16.0f, 0.0f, 0, false);
            whh8[j2] = (uint8_t)pk;
        }
        return;
    }
    const int sub = tid >> 6, t64 = tid & 63;
    const int cid = ((int)blockIdx.x - 8000) * 4 + sub;   // 0..7935
    const int w = cid % 31;
    const int bg = cid / 31;
    const int b = bg >> 1, g = bg & 1;
    if (t64 < 31) {
        int s = w * 16 + t64;
        const float4 x0 = *(const float4*)(x + ((size_t)b * 512 + s) * 4);
        const float4 x1 = *(const float4*)(x + ((size_t)b * 512 + s + 1) * 4);
        float d0 = x1.x - x0.x, d1 = x1.y - x0.y, d2 = x1.z - x0.z, d3 = x1.w - x0.w;
        dxs[sub][t64][0] = d0; dxs[sub][t64][1] = d1;
        dxs[sub][t64][2] = d2; dxs[sub][t64][3] = d3;
        dxs[sub][t64][4] = 1.0f / 511.0f;
#pragma unroll
        for (int e = 0; e < 5; e++) {
            const float* wa = W_aug + (g * 5 + e) * 4;
            dxs[sub][t64][5 + e] = d0 * wa[0] + d1 * wa[1] + d2 * wa[2] + d3 * wa[3];
        }
    }
    __syncthreads();
    size_t base = ((size_t)(w * 128 + b)) * 2240 + (size_t)g * 1110;
    if (t64 < 50) {
        int p0 = 2 * t64, p1 = p0 + 1;
        int i0 = p0 / 10, j0 = p0 % 10, j1 = j0 + 1;
        float s3a[10], s3b[10];
#pragma unroll
        for (int k = 0; k < 10; k++) { s3a[k] = 0.f; s3b[k] = 0.f; }
        float s2a = 0.f, s2b = 0.f, s1 = 0.f;
        for (int l = 0; l < 31; l++) {
            float dx[10];
#pragma unroll
            for (int c = 0; c < 10; c++) dx[c] = dxs[sub][l][c];
            float t0 = s1 + dx[i0] * (1.0f / 3.0f);
            float a0 = s2a + t0 * (0.5f * dx[j0]);
            float a1 = s2b + t0 * (0.5f * dx[j1]);
#pragma unroll
            for (int k = 0; k < 10; k++) { s3a[k] += a0 * dx[k]; s3b[k] += a1 * dx[k]; }
            float u = s1 + 0.5f * dx[i0];
            s2a += u * dx[j0];
            s2b += u * dx[j1];
            s1 += dx[i0];
        }
        sig16[base + 10 + p0] = (f16)s2a;
        sig16[base + 10 + p1] = (f16)s2b;
#pragma unroll
        for (int k = 0; k < 10; k++) {
            sig16[base + 110 + p0 * 10 + k] = (f16)s3a[k];
            sig16[base + 110 + p1 * 10 + k] = (f16)s3b[k];
        }
    } else if (t64 < 60) {
        int c = t64 - 50;
        float s = 0.f;
        for (int l = 0; l < 31; l++) s += dxs[sub][l][c];
        sig16[base + c] = (f16)s;
    }
    if (g == 1 && t64 < 20)
        sig16[((size_t)(w * 128 + b)) * 2240 + 2220 + t64] = (f16)0.0f;
}

// ---------------------------------------------------------------- K2: gi = sig @ W_ih.T + biases (f16, GRU lane order)
__global__ __launch_bounds__(256) void gemm_kernel(const f16* __restrict__ A,     // 3968 x 2240
                                                   const f16* __restrict__ Bw,    // 768 x 2240
                                                   const float* __restrict__ bias,
                                                   const float* __restrict__ bhh,
                                                   f16* __restrict__ Cgi) {
    __shared__ __align__(16) f16 As[128 * 32];
    __shared__ __align__(16) f16 Bs[128 * 32];
    const int tid = threadIdx.x, lane = tid & 63, wid = tid >> 6;
    const int wm = wid >> 1, wn = wid & 1;
    const int Mbase = blockIdx.y * 128, Nbase = blockIdx.x * 128;
    const int lr = lane >> 2;
    const int lk = lane & 3;
    const int l16 = lane & 15, quad = lane >> 4;
    f32x4 acc[4][4];
#pragma unroll
    for (int mt = 0; mt < 4; mt++)
#pragma unroll
        for (int nt = 0; nt < 4; nt++) acc[mt][nt] = (f32x4){0.f, 0.f, 0.f, 0.f};

    for (int kt = 0; kt < 70; kt++) {
        const int k0 = kt * 32;
#pragma unroll
        for (int q = 0; q < 2; q++) {
            int r0 = wid * 32 + q * 16;
            const f16* ga = A + (size_t)(Mbase + r0 + lr) * 2240 + k0 + lk * 8;
            ASYNC16(ga, &As[r0 * 32]);
            const f16* gb = Bw + (size_t)(Nbase + r0 + lr) * 2240 + k0 + lk * 8;
            ASYNC16(gb, &Bs[r0 * 32]);
        }
        __syncthreads();
        f16x8 af[4], bf[4];
#pragma unroll
        for (int mt = 0; mt < 4; mt++)
            af[mt] = *(const f16x8*)&As[(wm * 64 + mt * 16 + l16) * 32 + quad * 8];
#pragma unroll
        for (int nt = 0; nt < 4; nt++)
            bf[nt] = *(const f16x8*)&Bs[(wn * 64 + nt * 16 + l16) * 32 + quad * 8];
#pragma unroll
        for (int mt = 0; mt < 4; mt++)
#pragma unroll
            for (int nt = 0; nt < 4; nt++)
                acc[mt][nt] = __builtin_amdgcn_mfma_f32_16x16x32_f16(af[mt], bf[nt], acc[mt][nt], 0, 0, 0);
        __syncthreads();
    }
    const int t = blockIdx.y;
#pragma unroll
    for (int mt = 0; mt < 4; mt++) {
        const int bbv = wm * 4 + mt;
#pragma unroll
        for (int nt = 0; nt < 4; nt++) {
            int col = Nbase + wn * 64 + nt * 16 + l16;
            float bv = bias[col] + (col < 512 ? bhh[col] : 0.0f);   // fold b_hh into r,z
            int gs = col >> 8, hcc = col & 255;
            int gw = hcc >> 5, gtc = (hcc >> 4) & 1, gl = hcc & 15;
            int gtid = gw * 64 + quad * 16 + gl;
            size_t off = ((size_t)(t * 8 + bbv) * 512 + gtid) * 24 + (gs * 2 + gtc) * 4;
            f16x4 st;
#pragma unroll
            for (int rr = 0; rr < 4; rr++) st[rr] = (f16)(acc[mt][nt][rr] + bv);
            *(f16x4*)(Cgi + off) = st;
        }
    }
}

// ---------------------------------------------------------------- K3: GRU scan
// 8 blocks x 512 threads. Wave owns h-cols [wid*32,+32).
// fp8 rz frags a[0:63], f16 n frags a[64:127], acc a[128:151] (152 AGPRs pinned).

#define ACLOB \
  "a0","a1","a2","a3","a4","a5","a6","a7","a8","a9","a10","a11","a12","a13","a14","a15", \
  "a16","a17","a18","a19","a20","a21","a22","a23","a24","a25","a26","a27","a28","a29","a30","a31", \
  "a32","a33","a34","a35","a36","a37","a38","a39","a40","a41","a42","a43","a44","a45","a46","a47", \
  "a48","a49","a50","a51","a52","a53","a54","a55","a56","a57","a58","a59","a60","a61","a62","a63", \
  "a64","a65","a66","a67","a68","a69","a70","a71","a72","a73","a74","a75","a76","a77","a78","a79", \
  "a80","a81","a82","a83","a84","a85","a86","a87","a88","a89","a90","a91","a92","a93","a94","a95", \
  "a96","a97","a98","a99","a100","a101","a102","a103","a104","a105","a106","a107","a108","a109","a110","a111", \
  "a112","a113","a114","a115","a116","a117","a118","a119","a120","a121","a122","a123","a124","a125","a126","a127", \
  "a128","a129","a130","a131","a132","a133","a134","a135","a136","a137","a138","a139","a140","a141","a142","a143", \
  "a144","a145","a146","a147","a148","a149","a150","a151"

// load fp8 rz fragment (8B) into AGPR pair
#define LF8(A0,A1, U, KT) do { \
  f32x2 _t = *(const f32x2*)(whh8 + (size_t)(((U) >> 1) * 256 + wid * 32 + ((U) & 1) * 16 + l16) * 256 + (KT) * 32 + quad * 8); \
  asm volatile("v_accvgpr_write_b32 a" #A0 ", %0\n\t" \
               "v_accvgpr_write_b32 a" #A1 ", %1" \
               :: "v"(_t[0]), "v"(_t[1]) : "a" #A0, "a" #A1); } while (0)

// load f16 n-gate fragment (16B) into AGPR quad
#define LFN(A0,A1,A2,A3, TC, KT) do { \
  f32x4 _t = *(const f32x4*)(whh16 + (size_t)(512 + wid * 32 + (TC) * 16 + l16) * 256 + (KT) * 32 + quad * 8); \
  asm volatile("v_accvgpr_write_b32 a" #A0 ", %0\n\t" \
               "v_accvgpr_write_b32 a" #A1 ", %1\n\t" \
               "v_accvgpr_write_b32 a" #A2 ", %2\n\t" \
               "v_accvgpr_write_b32 a" #A3 ", %3" \
               :: "v"(_t[0]), "v"(_t[1]), "v"(_t[2]), "v"(_t[3]) \
               : "a" #A0, "a" #A1, "a" #A2, "a" #A3); } while (0)

#define FP8G(P, F0,F1,F2,F3) \
  "v_mfma_f32_16x16x32_fp8_fp8 a[128:131], " P ", a[" F0 "], a[128:131]\n\t" \
  "v_mfma_f32_16x16x32_fp8_fp8 a[132:135], " P ", a[" F1 "], a[132:135]\n\t" \
  "v_mfma_f32_16x16x32_fp8_fp8 a[136:139], " P ", a[" F2 "], a[136:139]\n\t" \
  "v_mfma_f32_16x16x32_fp8_fp8 a[140:143], " P ", a[" F3 "], a[140:143]\n\t"

#define F16G(Q, G0,G1) \
  "v_mfma_f32_16x16x32_f16 a[144:147], " Q ", a[" G0 "], a[144:147]\n\t" \
  "v_mfma_f32_16x16x32_f16 a[148:151], " Q ", a[" G1 "], a[148:151]\n\t"

__global__ __launch_bounds__(512, 2) void gru_kernel(const f16* __restrict__ gi,
                                                     const f16* __restrict__ whh16,
                                                     const uint8_t* __restrict__ whh8,
                                                     const float* __restrict__ b_hh,
                                                     const float* __restrict__ W_out,
                                                     const float* __restrict__ b_out,
                                                     float* __restrict__ out) {
    __shared__ __align__(16) f16 hbufF[2][16 * 280];      // f16 h (n-gate A + head)
    __shared__ __align__(16) uint8_t hbuf8[2][16 * 272];  // fp8 h (rz A)
    const int tid = threadIdx.x, lane = tid & 63, wid = tid >> 6;   // wid 0..7
    const int quad = lane >> 4, l16 = lane & 15;
    const int bb = blockIdx.x;

    for (int i = tid; i < 16 * 280; i += 512) hbufF[1][i] = (f16)0.0f;
    for (int i = tid; i < 16 * 272; i += 512) hbuf8[1][i] = 0;

    // ---- pin fragments: rz fp8 -> a[2*(u*8+kt)], n f16 -> a[64+4*(tc*8+kt)]
    LF8(0,1, 0,0);   LF8(2,3, 0,1);   LF8(4,5, 0,2);   LF8(6,7, 0,3);
    LF8(8,9, 0,4);   LF8(10,11, 0,5); LF8(12,13, 0,6); LF8(14,15, 0,7);
    LF8(16,17, 1,0); LF8(18,19, 1,1); LF8(20,21, 1,2); LF8(22,23, 1,3);
    LF8(24,25, 1,4); LF8(26,27, 1,5); LF8(28,29, 1,6); LF8(30,31, 1,7);
    LF8(32,33, 2,0); LF8(34,35, 2,1); LF8(36,37, 2,2); LF8(38,39, 2,3);
    LF8(40,41, 2,4); LF8(42,43, 2,5); LF8(44,45, 2,6); LF8(46,47, 2,7);
    LF8(48,49, 3,0); LF8(50,51, 3,1); LF8(52,53, 3,2); LF8(54,55, 3,3);
    LF8(56,57, 3,4); LF8(58,59, 3,5); LF8(60,61, 3,6); LF8(62,63, 3,7);
    LFN(64,65,66,67,   0,0); LFN(68,69,70,71,   0,1); LFN(72,73,74,75,   0,2); LFN(76,77,78,79,   0,3);
    LFN(80,81,82,83,   0,4); LFN(84,85,86,87,   0,5); LFN(88,89,90,91,   0,6); LFN(92,93,94,95,   0,7);
    LFN(96,97,98,99,   1,0); LFN(100,101,102,103, 1,1); LFN(104,105,106,107, 1,2); LFN(108,109,110,111, 1,3);
    LFN(112,113,114,115, 1,4); LFN(116,117,118,119, 1,5); LFN(120,121,122,123, 1,6); LFN(124,125,126,127, 1,7);

    float bhn[2];
#pragma unroll
    for (int tc = 0; tc < 2; tc++) bhn[tc] = b_hh[512 + wid * 32 + tc * 16 + l16];
    float hm[2][4];
#pragma unroll
    for (int tc = 0; tc < 2; tc++)
#pragma unroll
        for (int rr = 0; rr < 4; rr++) hm[tc][rr] = 0.f;

    uint32_t aF0 = (uint32_t)(uintptr_t)(__attribute__((address_space(3))) const void*)
                       (&hbufF[0][l16 * 280 + quad * 8]);
    uint32_t aF1 = (uint32_t)(uintptr_t)(__attribute__((address_space(3))) const void*)
                       (&hbufF[1][l16 * 280 + quad * 8]);
    uint32_t a80 = (uint32_t)(uintptr_t)(__attribute__((address_space(3))) const void*)
                       (&hbuf8[0][l16 * 272 + quad * 8]);
    uint32_t a81 = (uint32_t)(uintptr_t)(__attribute__((address_space(3))) const void*)
                       (&hbuf8[1][l16 * 272 + quad * 8]);

    const size_t lanebase = ((size_t)bb * 512 + tid) * 24;
    f16x4 gcur[6];
#pragma unroll
    for (int i = 0; i < 6; i++) gcur[i] = *(const f16x4*)(gi + lanebase + i * 4);

    const float zerof = 0.0f;
    BAR_LDS();

    for (int t = 0; t < 31; t++) {
        const uint32_t a8 = (t & 1) ? a80 : a81;
        const uint32_t aF = (t & 1) ? aF0 : aF1;
        float cc[24];
        f32x2 p0, p1, p2;
        f32x4 q0, q1, q2;
        asm volatile(
            "ds_read_b64 %[p0], %[a8] offset:0\n\t"
            "ds_read_b64 %[p1], %[a8] offset:32\n\t"
            "ds_read_b64 %[p2], %[a8] offset:64\n\t"
            "v_accvgpr_write_b32 a128, %[z]\n\tv_accvgpr_write_b32 a129, %[z]\n\t"
            "v_accvgpr_write_b32 a130, %[z]\n\tv_accvgpr_write_b32 a131, %[z]\n\t"
            "v_accvgpr_write_b32 a132, %[z]\n\tv_accvgpr_write_b32 a133, %[z]\n\t"
            "v_accvgpr_write_b32 a134, %[z]\n\tv_accvgpr_write_b32 a135, %[z]\n\t"
            "v_accvgpr_write_b32 a136, %[z]\n\tv_accvgpr_write_b32 a137, %[z]\n\t"
            "v_accvgpr_write_b32 a138, %[z]\n\tv_accvgpr_write_b32 a139, %[z]\n\t"
            "v_accvgpr_write_b32 a140, %[z]\n\tv_accvgpr_write_b32 a141, %[z]\n\t"
            "v_accvgpr_write_b32 a142, %[z]\n\tv_accvgpr_write_b32 a143, %[z]\n\t"
            "v_accvgpr_write_b32 a144, %[z]\n\tv_accvgpr_write_b32 a145, %[z]\n\t"
            "v_accvgpr_write_b32 a146, %[z]\n\tv_accvgpr_write_b32 a147, %[z]\n\t"
            "v_accvgpr_write_b32 a148, %[z]\n\tv_accvgpr_write_b32 a149, %[z]\n\t"
            "v_accvgpr_write_b32 a150, %[z]\n\tv_accvgpr_write_b32 a151, %[z]\n\t"
            "s_waitcnt lgkmcnt(2)\n\t"
            FP8G("%[p0]", "0:1","16:17","32:33","48:49")
            "s_waitcnt lgkmcnt(1)\n\t"
            FP8G("%[p1]", "2:3","18:19","34:35","50:51")
            "ds_read_b64 %[p0], %[a8] offset:96\n\t"
            "s_waitcnt lgkmcnt(1)\n\t"
            FP8G("%[p2]", "4:5","20:21","36:37","52:53")
            "ds_read_b64 %[p1], %[a8] offset:128\n\t"
            "s_waitcnt lgkmcnt(1)\n\t"
            FP8G("%[p0]", "6:7","22:23","38:39","54:55")
            "ds_read_b64 %[p2], %[a8] offset:160\n\t"
            "s_waitcnt lgkmcnt(1)\n\t"
            FP8G("%[p1]", "8:9","24:25","40:41","56:57")
            "ds_read_b64 %[p0], %[a8] offset:192\n\t"
            "s_waitcnt lgkmcnt(1)\n\t"
            FP8G("%[p2]", "10:11","26:27","42:43","58:59")
            "ds_read_b64 %[p1], %[a8] offset:224\n\t"
            "ds_read_b128 %[q0], %[aF] offset:0\n\t"
            "s_waitcnt lgkmcnt(2)\n\t"
            FP8G("%[p0]", "12:13","28:29","44:45","60:61")
            "ds_read_b128 %[q1], %[aF] offset:64\n\t"
            "s_waitcnt lgkmcnt(2)\n\t"
            FP8G("%[p1]", "14:15","30:31","46:47","62:63")
            "ds_read_b128 %[q2], %[aF] offset:128\n\t"
            "s_waitcnt lgkmcnt(2)\n\t"
            F16G("%[q0]", "64:67","96:99")
            "ds_read_b128 %[q0], %[aF] offset:192\n\t"
            "s_waitcnt lgkmcnt(2)\n\t"
            F16G("%[q1]", "68:71","100:103")
            "ds_read_b128 %[q1], %[aF] offset:256\n\t"
            "s_waitcnt lgkmcnt(2)\n\t"
            F16G("%[q2]", "72:75","104:107")
            "ds_read_b128 %[q2], %[aF] offset:320\n\t"
            "s_waitcnt lgkmcnt(2)\n\t"
            F16G("%[q0]", "76:79","108:111")
            "ds_read_b128 %[q0], %[aF] offset:384\n\t"
            "s_waitcnt lgkmcnt(2)\n\t"
            F16G("%[q1]", "80:83","112:115")
            "ds_read_b128 %[q1], %[aF] offset:448\n\t"
            "s_waitcnt lgkmcnt(2)\n\t"
            F16G("%[q2]", "84:87","116:119")
            "s_waitcnt lgkmcnt(1)\n\t"
            F16G("%[q0]", "88:91","120:123")
            "s_waitcnt lgkmcnt(0)\n\t"
            F16G("%[q1]", "92:95","124:127")
            "s_nop 7\n\ts_nop 7\n\ts_nop 7\n\t"
            "v_accvgpr_read_b32 %[c0], a128\n\tv_accvgpr_read_b32 %[c1], a129\n\t"
            "v_accvgpr_read_b32 %[c2], a130\n\tv_accvgpr_read_b32 %[c3], a131\n\t"
            "v_accvgpr_read_b32 %[c4], a132\n\tv_accvgpr_read_b32 %[c5], a133\n\t"
            "v_accvgpr_read_b32 %[c6], a134\n\tv_accvgpr_read_b32 %[c7], a135\n\t"
            "v_accvgpr_read_b32 %[c8], a136\n\tv_accvgpr_read_b32 %[c9], a137\n\t"
            "v_accvgpr_read_b32 %[c10], a138\n\tv_accvgpr_read_b32 %[c11], a139\n\t"
            "v_accvgpr_read_b32 %[c12], a140\n\tv_accvgpr_read_b32 %[c13], a141\n\t"
            "v_accvgpr_read_b32 %[c14], a142\n\tv_accvgpr_read_b32 %[c15], a143\n\t"
            "v_accvgpr_read_b32 %[c16], a144\n\tv_accvgpr_read_b32 %[c17], a145\n\t"
            "v_accvgpr_read_b32 %[c18], a146\n\tv_accvgpr_read_b32 %[c19], a147\n\t"
            "v_accvgpr_read_b32 %[c20], a148\n\tv_accvgpr_read_b32 %[c21], a149\n\t"
            "v_accvgpr_read_b32 %[c22], a150\n\tv_accvgpr_read_b32 %[c23], a151"
            : [c0]"=v"(cc[0]), [c1]"=v"(cc[1]), [c2]"=v"(cc[2]), [c3]"=v"(cc[3]),
              [c4]"=v"(cc[4]), [c5]"=v"(cc[5]), [c6]"=v"(cc[6]), [c7]"=v"(cc[7]),
              [c8]"=v"(cc[8]), [c9]"=v"(cc[9]), [c10]"=v"(cc[10]), [c11]"=v"(cc[11]),
              [c12]"=v"(cc[12]), [c13]"=v"(cc[13]), [c14]"=v"(cc[14]), [c15]"=v"(cc[15]),
              [c16]"=v"(cc[16]), [c17]"=v"(cc[17]), [c18]"=v"(cc[18]), [c19]"=v"(cc[19]),
              [c20]"=v"(cc[20]), [c21]"=v"(cc[21]), [c22]"=v"(cc[22]), [c23]"=v"(cc[23]),
              [p0]"=&v"(p0), [p1]"=&v"(p1), [p2]"=&v"(p2),
              [q0]"=&v"(q0), [q1]"=&v"(q1), [q2]"=&v"(q2)
            : [a8]"v"(a8), [aF]"v"(aF), [z]"v"(zerof)
            : ACLOB);

        // gate math: cc[(gs*2+tc)*4+rr] rz (x1/16), cc[16+tc*4+rr] n
        f16* hdF = hbufF[t & 1];
        uint8_t* hd8 = hbuf8[t & 1];
#pragma unroll
        for (int tc = 0; tc < 2; tc++) {
            const int hcx = wid * 32 + tc * 16 + l16;
#pragma unroll
            for (int rr = 0; rr < 4; rr++) {
                float rg = 1.f / (1.f + __expf(-fmaf(0.0625f, cc[tc * 4 + rr], (float)gcur[tc][rr])));
                float zg = 1.f / (1.f + __expf(-fmaf(0.0625f, cc[(2 + tc) * 4 + rr], (float)gcur[2 + tc][rr])));
                float ar = fmaf(rg, cc[16 + tc * 4 + rr] + bhn[tc], (float)gcur[4 + tc][rr]);
                float e2 = __expf(2.f * ar);
                float ng = 1.f - 2.f / (e2 + 1.f);            // tanh(ar)
                float h = fmaf(zg, hm[tc][rr] - ng, ng);      // (1-z)n + z*h
                hm[tc][rr] = h;
                hdF[(quad * 4 + rr) * 280 + hcx] = (f16)h;
                int pk = __builtin_amdgcn_cvt_pk_fp8_f32(h, h, 0, false);
                hd8[(quad * 4 + rr) * 272 + hcx] = (uint8_t)pk;
            }
        }
        // prefetch gi for t+1 (registers; survives lgkm-only barrier)
        {
            int tn = (t < 30) ? t + 1 : 30;
            const f16* gsrc = gi + (size_t)tn * 98304 + lanebase;
#pragma unroll
            for (int i = 0; i < 6; i++) gcur[i] = *(const f16x4*)(gsrc + i * 4);
        }
        BAR_LDS();
    }
    // output head: final h in hbufF[0]
    if (tid < 160) {
        int r = tid / 10, oc = tid - r * 10;
        const f16* hfin = hbufF[0];
        float s = b_out[oc];
        for (int k = 0; k < 256; k++) s += (float)hfin[r * 280 + k] * W_out[oc * 256 + k];
        out[(bb * 16 + r) * 10 + oc] = 1.f / (1.f + __expf(-s));
    }
}

// ---------------------------------------------------------------- launch
extern "C" void kernel_launch(void* const* d_in, const int* in_sizes, int n_in,
                              void* d_out, int out_size, void* d_ws, size_t ws_size,
                              hipStream_t stream) {
    const float* x     = (const float*)d_in[0];
    const float* W_aug = (const float*)d_in[1];
    // d_in[2] = b_aug — cancels in dx, unused
    const float* W_ih  = (const float*)d_in[3];
    const float* W_hh  = (const float*)d_in[4];
    const float* b_ih  = (const float*)d_in[5];
    const float* b_hh  = (const float*)d_in[6];
    const float* W_out = (const float*)d_in[7];
    const float* b_out = (const float*)d_in[8];
    float* out = (float*)d_out;

    char* ws = (char*)d_ws;
    const size_t SIG_BYTES  = (size_t)3968 * 2240 * 2;           // 17,776,640
    const size_t WIH_BYTES  = (size_t)768 * 2240 * 2;            //  3,440,640
    const size_t WHH_BYTES  = (size_t)768 * 256 * 2;             //    393,216
    const size_t WHH8_BYTES = (size_t)512 * 256;                 //    131,072
    const size_t GI_BYTES   = (size_t)31 * 8 * 512 * 24 * 2;     //  6,094,848
    if (ws_size < SIG_BYTES + WIH_BYTES + WHH_BYTES + WHH8_BYTES + GI_BYTES) return;
    f16* sig16    = (f16*)ws;
    f16* wih16    = (f16*)(ws + SIG_BYTES);
    f16* whh16    = (f16*)(ws + SIG_BYTES + WIH_BYTES);
    uint8_t* whh8 = (uint8_t*)(ws + SIG_BYTES + WIH_BYTES + WHH_BYTES);
    f16* giw      = (f16*)(ws + SIG_BYTES + WIH_BYTES + WHH_BYTES + WHH8_BYTES);

    hipLaunchKernelGGL(prep_kernel, dim3(9984), dim3(256), 0, stream,
                       x, W_aug, W_ih, W_hh, sig16, wih16, whh16, whh8);
    hipLaunchKernelGGL(gemm_kernel, dim3(6, 31), dim3(256), 0, stream,
                       sig16, wih16, b_ih, b_hh, giw);
    hipLaunchKernelGGL(gru_kernel, dim3(8), dim3(512), 0, stream,
                       giw, whh16, whh8, b_hh, W_out, b_out, out);
}